// Round 2
// baseline (2962.299 us; speedup 1.0000x reference)
//
#include <hip/hip_runtime.h>
#include <math.h>

// ---------------------------------------------------------------------------
// Bidirectional Mamba encoder, fp32, round 2: occupancy + latency fixes.
// All GEMM kernels re-tiled for >=2 blocks/CU; k_embed/k_xz get register
// double-buffered global->LDS staging; k_scan widened to 8 t/iter.
// ---------------------------------------------------------------------------

#define L_SEQ 1031
#define LP    1032
#define BATCH 8
#define NVAR  1024
#define SEQQ  512
#define TFEAT 7

#define SZ_H    ((size_t)BATCH * L_SEQ * 128)
#define SZ_XZ   ((size_t)2 * BATCH * L_SEQ * 256)
#define SZ_DT   ((size_t)2 * BATCH * 128 * LP)
#define SZ_BC   ((size_t)2 * BATCH * 16 * LP)
#define OFF_H    ((size_t)0)
#define OFF_H1   (OFF_H + SZ_H)
#define OFF_XZ   (OFF_H1 + SZ_H)
#define OFF_XCT  (OFF_XZ + SZ_XZ)
#define OFF_DLT  (OFF_XCT + SZ_DT)
#define OFF_BMT  (OFF_DLT + SZ_DT)
#define OFF_CMT  (OFF_BMT + SZ_BC)
#define OFF_YT   (OFF_CMT + SZ_BC)

__device__ __forceinline__ float silu_f(float x) {
  return x / (1.f + __expf(-x));
}
__device__ __forceinline__ float softplus_f(float x) {
  return (x > 20.f) ? x : log1pf(__expf(x));
}

// ---------------------------------------------------------------------------
// k_embed: H[b,v,:] = token(b,v,:) @ emb_w.T + emb_b
// grid (65, 8), block 256. 16 v-rows x 128 m per block, BK=32, reg-dbuf.
// ---------------------------------------------------------------------------
__global__ __launch_bounds__(256) void k_embed(
    const float* __restrict__ x_enc, const float* __restrict__ x_mark,
    const float* __restrict__ emb_w, const float* __restrict__ emb_b,
    float* __restrict__ H) {
  int b = blockIdx.y;
  int v0 = blockIdx.x * 16;
  int tid = threadIdx.x;
  __shared__ float As[32][17];    // [s][v]
  __shared__ float Ws[32][144];   // [s][m]
  int tm = tid & 15, tt = tid >> 4;
  float acc[8] = {0.f};
  float aP[2], wP[16];
  // prefetch tile s0=0
#pragma unroll
  for (int i = 0; i < 2; i++) {
    int e = tid + i * 256;
    int vi = e & 15, si = e >> 4;
    int v = v0 + vi;
    float val = 0.f;
    if (v < L_SEQ) {
      if (v < NVAR) {
        val = x_enc[((size_t)b * SEQQ + si) * NVAR + v];
        if (val == -9999.f) val = -1.f;
      } else {
        val = x_mark[((size_t)b * SEQQ + si) * TFEAT + (v - NVAR)];
      }
    }
    aP[i] = val;
  }
#pragma unroll
  for (int i = 0; i < 16; i++) {
    int e = tid + i * 256;
    int si = e & 31, m = e >> 5;
    wP[i] = emb_w[(size_t)m * SEQQ + si];
  }
  for (int s0 = 0; s0 < SEQQ; s0 += 32) {
    // commit prefetched tile to LDS
#pragma unroll
    for (int i = 0; i < 2; i++) {
      int e = tid + i * 256;
      As[e >> 4][e & 15] = aP[i];
    }
#pragma unroll
    for (int i = 0; i < 16; i++) {
      int e = tid + i * 256;
      Ws[e & 31][e >> 5] = wP[i];
    }
    __syncthreads();
    // prefetch next tile
    if (s0 + 32 < SEQQ) {
#pragma unroll
      for (int i = 0; i < 2; i++) {
        int e = tid + i * 256;
        int vi = e & 15, si = e >> 4;
        int v = v0 + vi, s = s0 + 32 + si;
        float val = 0.f;
        if (v < L_SEQ) {
          if (v < NVAR) {
            val = x_enc[((size_t)b * SEQQ + s) * NVAR + v];
            if (val == -9999.f) val = -1.f;
          } else {
            val = x_mark[((size_t)b * SEQQ + s) * TFEAT + (v - NVAR)];
          }
        }
        aP[i] = val;
      }
#pragma unroll
      for (int i = 0; i < 16; i++) {
        int e = tid + i * 256;
        int si = e & 31, m = e >> 5;
        wP[i] = emb_w[(size_t)m * SEQQ + s0 + 32 + si];
      }
    }
    // compute
    for (int si = 0; si < 32; si++) {
      float a = As[si][tt];
      float w[8];
      *(float4*)&w[0] = *(const float4*)&Ws[si][tm * 8];
      *(float4*)&w[4] = *(const float4*)&Ws[si][tm * 8 + 4];
#pragma unroll
      for (int j = 0; j < 8; j++) acc[j] = fmaf(a, w[j], acc[j]);
    }
    __syncthreads();
  }
  int v = v0 + tt;
  if (v < L_SEQ) {
    float* dst = &H[((size_t)b * L_SEQ + v) * 128 + tm * 8];
#pragma unroll
    for (int j = 0; j < 8; j++) dst[j] = acc[j] + emb_b[tm * 8 + j];
  }
}

// ---------------------------------------------------------------------------
// k_xz: XZ[dir,b,t,nh*128:+128] = h_dir(b,t,:) @ ipw[l,dir,nh-half].T
// grid (33, 8, 4) z=(dir,nh), block 256. 32 t x 128 n, BK=32, reg-dbuf.
// ---------------------------------------------------------------------------
__global__ __launch_bounds__(256) void k_xz(
    const float* __restrict__ H, const float* __restrict__ ipw,
    float* __restrict__ XZ, int l) {
  int b = blockIdx.y;
  int dir = blockIdx.z >> 1, nh = blockIdx.z & 1;
  int t0 = blockIdx.x * 32;
  int tid = threadIdx.x;
  __shared__ float As[32][33];
  __shared__ float Ws[32][144];
  int tm = tid & 15, tt = tid >> 4;
  float acc[2][8] = {{0.f}};
  const float* wbase = ipw + (size_t)(l * 2 + dir) * 256 * 128 + (size_t)nh * 128 * 128;
  float aP[4], wP[16];
#pragma unroll
  for (int i = 0; i < 4; i++) {
    int e = tid + i * 256;
    int ki = e & 31, tl = e >> 5;
    int t = t0 + tl;
    float v = 0.f;
    if (t < L_SEQ) {
      int st = dir ? (L_SEQ - 1 - t) : t;
      v = H[((size_t)b * L_SEQ + st) * 128 + ki];
    }
    aP[i] = v;
  }
#pragma unroll
  for (int i = 0; i < 16; i++) {
    int e = tid + i * 256;
    int ki = e & 31, j = e >> 5;
    wP[i] = wbase[(size_t)j * 128 + ki];
  }
  for (int k0 = 0; k0 < 128; k0 += 32) {
#pragma unroll
    for (int i = 0; i < 4; i++) {
      int e = tid + i * 256;
      As[e & 31][e >> 5] = aP[i];
    }
#pragma unroll
    for (int i = 0; i < 16; i++) {
      int e = tid + i * 256;
      Ws[e & 31][e >> 5] = wP[i];
    }
    __syncthreads();
    if (k0 + 32 < 128) {
#pragma unroll
      for (int i = 0; i < 4; i++) {
        int e = tid + i * 256;
        int ki = e & 31, tl = e >> 5;
        int t = t0 + tl;
        float v = 0.f;
        if (t < L_SEQ) {
          int st = dir ? (L_SEQ - 1 - t) : t;
          v = H[((size_t)b * L_SEQ + st) * 128 + k0 + 32 + ki];
        }
        aP[i] = v;
      }
#pragma unroll
      for (int i = 0; i < 16; i++) {
        int e = tid + i * 256;
        int ki = e & 31, j = e >> 5;
        wP[i] = wbase[(size_t)j * 128 + k0 + 32 + ki];
      }
    }
    for (int ki = 0; ki < 32; ki++) {
      float a0 = As[ki][tt * 2], a1 = As[ki][tt * 2 + 1];
      float w[8];
      *(float4*)&w[0] = *(const float4*)&Ws[ki][tm * 8];
      *(float4*)&w[4] = *(const float4*)&Ws[ki][tm * 8 + 4];
#pragma unroll
      for (int j = 0; j < 8; j++) {
        acc[0][j] = fmaf(a0, w[j], acc[0][j]);
        acc[1][j] = fmaf(a1, w[j], acc[1][j]);
      }
    }
    __syncthreads();
  }
#pragma unroll
  for (int r = 0; r < 2; r++) {
    int t = t0 + tt * 2 + r;
    if (t < L_SEQ) {
      float* dst = XZ + ((size_t)(dir * BATCH + b) * L_SEQ + t) * 256 + nh * 128 + tm * 8;
      *(float4*)&dst[0] = *(float4*)&acc[r][0];
      *(float4*)&dst[4] = *(float4*)&acc[r][4];
    }
  }
}

// ---------------------------------------------------------------------------
// k_mid: conv+silu -> xc ; dbc = xc @ xpw.T ; delta=softplus(dt@dpw.T+dpb)
// grid (33, 8, 2), block 256, 32-t tiles.
// ---------------------------------------------------------------------------
__global__ __launch_bounds__(256) void k_mid(
    const float* __restrict__ XZ,
    const float* __restrict__ conv_w, const float* __restrict__ conv_b,
    const float* __restrict__ xpw,
    const float* __restrict__ dpw, const float* __restrict__ dpb,
    float* __restrict__ XCT, float* __restrict__ DLT,
    float* __restrict__ BmT, float* __restrict__ CmT, int l) {
  int b = blockIdx.y, dir = blockIdx.z;
  int t0 = blockIdx.x * 32;
  int tid = threadIdx.x;
  int pg = l * 2 + dir;
  __shared__ float xcs[32][132];
  __shared__ float xpws[40][128];
  __shared__ float dbcs[40][36];
  const float* xz = XZ + (size_t)(dir * BATCH + b) * L_SEQ * 256;

  for (int i = 0; i < 20; i++) {
    int e = tid + i * 256;
    int k = e & 127, j = e >> 7;
    xpws[j][k] = xpw[((size_t)pg * 40 + j) * 128 + k];
  }
  for (int i = 0; i < 16; i++) {
    int e = tid + i * 256;
    int d = e & 127, tl = e >> 7;
    int t = t0 + tl;
    float v = 0.f;
    if (t < L_SEQ) {
      float x1 = xz[(size_t)t * 256 + d];
      float x0 = (t > 0) ? xz[(size_t)(t - 1) * 256 + d] : 0.f;
      float c0 = conv_w[((size_t)pg * 128 + d) * 2 + 0];
      float c1 = conv_w[((size_t)pg * 128 + d) * 2 + 1];
      v = silu_f(x0 * c0 + x1 * c1 + conv_b[(size_t)pg * 128 + d]);
    }
    xcs[tl][d] = v;
  }
  __syncthreads();
  // dbc = xc @ xpw.T  (32 t x 40 j, K=128)
  {
    int tl = tid & 31, jg = tid >> 5;   // jg in 0..7, 5 j each
    float acc[5] = {0.f};
    const float4* xrow = (const float4*)&xcs[tl][0];
    for (int kk = 0; kk < 32; kk++) {
      float4 a = xrow[kk];
#pragma unroll
      for (int jj = 0; jj < 5; jj++) {
        float4 w = ((const float4*)&xpws[jg * 5 + jj][0])[kk];
        acc[jj] = fmaf(a.x, w.x, acc[jj]);
        acc[jj] = fmaf(a.y, w.y, acc[jj]);
        acc[jj] = fmaf(a.z, w.z, acc[jj]);
        acc[jj] = fmaf(a.w, w.w, acc[jj]);
      }
    }
#pragma unroll
    for (int jj = 0; jj < 5; jj++) dbcs[jg * 5 + jj][tl] = acc[jj];
  }
  __syncthreads();
  // Bm/Cm transposed stores
  for (int i = 0; i < 4; i++) {
    int e = tid + i * 256;
    int tl = e & 31, r = e >> 5;
    int n = r & 15, isC = r >> 4;
    int t = t0 + tl;
    if (t < LP) {
      float v = dbcs[8 + isC * 16 + n][tl];
      float* dst = isC ? CmT : BmT;
      dst[((size_t)(dir * BATCH + b) * 16 + n) * LP + t] = v;
    }
  }
  // delta/xct transposed stores
  {
    int d = tid & 127, th = tid >> 7;
    float dw[8];
#pragma unroll
    for (int k = 0; k < 8; k++) dw[k] = dpw[((size_t)pg * 128 + d) * 8 + k];
    float dbv = dpb[(size_t)pg * 128 + d];
    size_t base = ((size_t)(dir * BATCH + b) * 128 + d) * LP;
    for (int tb = th * 16; tb < th * 16 + 16; tb += 4) {
      int t = t0 + tb;
      if (t < LP) {
        float dv[4], xv[4];
#pragma unroll
        for (int u = 0; u < 4; u++) {
          int tl = tb + u;
          float a = dbv;
#pragma unroll
          for (int k = 0; k < 8; k++) a = fmaf(dbcs[k][tl], dw[k], a);
          dv[u] = softplus_f(a);
          xv[u] = xcs[tl][d];
        }
        *(float4*)(DLT + base + t) = make_float4(dv[0], dv[1], dv[2], dv[3]);
        *(float4*)(XCT + base + t) = make_float4(xv[0], xv[1], xv[2], xv[3]);
      }
    }
  }
}

// ---------------------------------------------------------------------------
// k_scan: selective scan, 8 t per iteration, depth-1 prefetch.
// grid (16, 8, 2), block 64 (one wave: 8 d x 8 lane-pairs of 2 states).
// ---------------------------------------------------------------------------
__global__ __launch_bounds__(64) void k_scan(
    const float* __restrict__ DLT, const float* __restrict__ XCT,
    const float* __restrict__ BmT, const float* __restrict__ CmT,
    const float* __restrict__ A_log, const float* __restrict__ Dpar,
    float* __restrict__ YT, int l) {
  int dir = blockIdx.z, b = blockIdx.y;
  int lane = threadIdx.x;
  int np = lane & 7, ds = lane >> 3;
  int d = blockIdx.x * 8 + ds;
  int pg = l * 2 + dir;
  int n0 = np * 2;
  float A0 = -__expf(A_log[((size_t)pg * 128 + d) * 16 + n0]);
  float A1 = -__expf(A_log[((size_t)pg * 128 + d) * 16 + n0 + 1]);
  float Dv = Dpar[(size_t)pg * 128 + d];
  size_t bd = ((size_t)(dir * BATCH + b) * 128 + d) * LP;
  size_t bn = ((size_t)(dir * BATCH + b) * 16 + n0) * LP;
  const float4* dl4 = (const float4*)(DLT + bd);
  const float4* xc4 = (const float4*)(XCT + bd);
  const float4* b04 = (const float4*)(BmT + bn);
  const float4* b14 = (const float4*)(BmT + bn + LP);
  const float4* c04 = (const float4*)(CmT + bn);
  const float4* c14 = (const float4*)(CmT + bn + LP);
  float4* y4 = (float4*)(YT + bd);
  float h0 = 0.f, h1 = 0.f;
  const int NC = LP / 8;   // 129
  float4 cd0 = dl4[0], cd1 = dl4[1], cx0 = xc4[0], cx1 = xc4[1];
  float4 cb00 = b04[0], cb01 = b04[1], cb10 = b14[0], cb11 = b14[1];
  float4 cc00 = c04[0], cc01 = c04[1], cc10 = c14[0], cc11 = c14[1];
#define STEP1(DL, XC, B0, B1, C0, C1, YO)                \
  {                                                      \
    float du_ = (DL) * (XC);                             \
    h0 = fmaf(__expf((DL) * A0), h0, du_ * (B0));        \
    h1 = fmaf(__expf((DL) * A1), h1, du_ * (B1));        \
    float p_ = fmaf(h1, (C1), h0 * (C0));                \
    p_ += __shfl_xor(p_, 1);                             \
    p_ += __shfl_xor(p_, 2);                             \
    p_ += __shfl_xor(p_, 4);                             \
    (YO) = fmaf(Dv, (XC), p_);                           \
  }
#define STEP4(D4, X4, B04, B14, C04, C14, Y4)                    \
  STEP1((D4).x, (X4).x, (B04).x, (B14).x, (C04).x, (C14).x, (Y4).x) \
  STEP1((D4).y, (X4).y, (B04).y, (B14).y, (C04).y, (C14).y, (Y4).y) \
  STEP1((D4).z, (X4).z, (B04).z, (B14).z, (C04).z, (C14).z, (Y4).z) \
  STEP1((D4).w, (X4).w, (B04).w, (B14).w, (C04).w, (C14).w, (Y4).w)
  for (int i = 0; i < NC; i++) {
    float4 nd0 = cd0, nd1 = cd1, nx0 = cx0, nx1 = cx1;
    float4 nb00 = cb00, nb01 = cb01, nb10 = cb10, nb11 = cb11;
    float4 nc00 = cc00, nc01 = cc01, nc10 = cc10, nc11 = cc11;
    if (i + 1 < NC) {
      int o = 2 * (i + 1);
      nd0 = dl4[o]; nd1 = dl4[o + 1]; nx0 = xc4[o]; nx1 = xc4[o + 1];
      nb00 = b04[o]; nb01 = b04[o + 1]; nb10 = b14[o]; nb11 = b14[o + 1];
      nc00 = c04[o]; nc01 = c04[o + 1]; nc10 = c14[o]; nc11 = c14[o + 1];
    }
    float4 y0, y1;
    STEP4(cd0, cx0, cb00, cb10, cc00, cc10, y0);
    STEP4(cd1, cx1, cb01, cb11, cc01, cc11, y1);
    if (np == 0) {
      y4[2 * i] = y0;
      y4[2 * i + 1] = y1;
    }
    cd0 = nd0; cd1 = nd1; cx0 = nx0; cx1 = nx1;
    cb00 = nb00; cb01 = nb01; cb10 = nb10; cb11 = nb11;
    cc00 = nc00; cc01 = nc01; cc10 = nc10; cc11 = nc11;
  }
#undef STEP4
#undef STEP1
}

// ---------------------------------------------------------------------------
// k_out: H1 = layernorm1( H + (yf*silu(zf))@opw_f.T + (yr*silu(zr))@opw_r.T )
// grid (65, 8), block 256. 16 t x 128 m per block.
// ---------------------------------------------------------------------------
__global__ __launch_bounds__(256) void k_out(
    const float* __restrict__ YT, const float* __restrict__ XZ,
    const float* __restrict__ Hin, const float* __restrict__ opw,
    const float* __restrict__ n1w, const float* __restrict__ n1b,
    float* __restrict__ H1, int l) {
  int b = blockIdx.y;
  int t0 = blockIdx.x * 16;
  int tid = threadIdx.x;
  __shared__ float Af[128][17];
  __shared__ float Ar[128][17];
  __shared__ float Ws[32][144];
  for (int i = 0; i < 8; i++) {
    int e = tid + i * 256;
    int tl = e & 15, k = e >> 4;
    int t = t0 + tl;
    float vf = 0.f, vr = 0.f;
    if (t < L_SEQ) {
      vf = YT[((size_t)b * 128 + k) * LP + t];
      vr = YT[((size_t)(BATCH + b) * 128 + k) * LP + (L_SEQ - 1 - t)];
    }
    Af[k][tl] = vf;
    Ar[k][tl] = vr;
  }
  __syncthreads();
  for (int i = 0; i < 8; i++) {
    int e = tid + i * 256;
    int k = e & 127, tl = e >> 7;
    int t = t0 + tl;
    if (t < L_SEQ) {
      float zf = XZ[((size_t)b * L_SEQ + t) * 256 + 128 + k];
      float zr = XZ[((size_t)(BATCH + b) * L_SEQ + (L_SEQ - 1 - t)) * 256 + 128 + k];
      Af[k][tl] *= silu_f(zf);
      Ar[k][tl] *= silu_f(zr);
    }
  }
  __syncthreads();
  int tm = tid & 15, tt = tid >> 4;
  float acc[8] = {0.f};
  for (int dirp = 0; dirp < 2; dirp++) {
    const float* wsrc = opw + (size_t)(l * 2 + dirp) * 128 * 128;
    const float(*Acur)[17] = dirp ? Ar : Af;
    for (int k0 = 0; k0 < 128; k0 += 32) {
      for (int i = 0; i < 16; i++) {
        int e = tid + i * 256;
        int ki = e & 31, m = e >> 5;
        Ws[ki][m] = wsrc[(size_t)m * 128 + k0 + ki];
      }
      __syncthreads();
      for (int ki = 0; ki < 32; ki++) {
        float a = Acur[k0 + ki][tt];
        float w[8];
        *(float4*)&w[0] = *(const float4*)&Ws[ki][tm * 8];
        *(float4*)&w[4] = *(const float4*)&Ws[ki][tm * 8 + 4];
#pragma unroll
        for (int j = 0; j < 8; j++) acc[j] = fmaf(a, w[j], acc[j]);
      }
      __syncthreads();
    }
  }
  const float* nw = n1w + l * 128;
  const float* nb = n1b + l * 128;
  int t = t0 + tt;
  float resid[8] = {0.f};
  if (t < L_SEQ) {
    const float4* hp = (const float4*)&Hin[((size_t)b * L_SEQ + t) * 128 + tm * 8];
    *(float4*)&resid[0] = hp[0];
    *(float4*)&resid[4] = hp[1];
  }
  float val[8], s1 = 0.f, s2 = 0.f;
#pragma unroll
  for (int j = 0; j < 8; j++) {
    float v = acc[j] + resid[j];
    val[j] = v;
    s1 += v;
    s2 += v * v;
  }
#pragma unroll
  for (int msk = 1; msk < 16; msk <<= 1) {
    s1 += __shfl_xor(s1, msk);
    s2 += __shfl_xor(s2, msk);
  }
  float mean = s1 * (1.f / 128.f);
  float rstd = rsqrtf(s2 * (1.f / 128.f) - mean * mean + 1e-5f);
  if (t < L_SEQ) {
    float* dst = &H1[((size_t)b * L_SEQ + t) * 128 + tm * 8];
#pragma unroll
    for (int j = 0; j < 8; j++)
      dst[j] = (val[j] - mean) * rstd * nw[tm * 8 + j] + nb[tm * 8 + j];
  }
}

// ---------------------------------------------------------------------------
// k_ffn: H = layernorm2( h1 + relu(h1@w1.T+b1)@w2.T + b2 )
// grid (65, 8), block 256. 16 t per block.
// ---------------------------------------------------------------------------
__global__ __launch_bounds__(256) void k_ffn(
    const float* __restrict__ H1, const float* __restrict__ w1,
    const float* __restrict__ b1, const float* __restrict__ w2,
    const float* __restrict__ b2, const float* __restrict__ n2w,
    const float* __restrict__ n2b, float* __restrict__ Hout, int l) {
  int b = blockIdx.y;
  int t0 = blockIdx.x * 16;
  int tid = threadIdx.x;
  __shared__ float At[128][17];
  __shared__ float Ut[128][17];
  __shared__ float Ws[32][144];
  for (int i = 0; i < 8; i++) {
    int e = tid + i * 256;
    int k = e & 127, tl = e >> 7;
    int t = t0 + tl;
    At[k][tl] = (t < L_SEQ) ? H1[((size_t)b * L_SEQ + t) * 128 + k] : 0.f;
  }
  __syncthreads();
  int tm = tid & 15, tt = tid >> 4;
  float acc[8] = {0.f};
  const float* w1b = w1 + (size_t)l * 128 * 128;
  for (int k0 = 0; k0 < 128; k0 += 32) {
    for (int i = 0; i < 16; i++) {
      int e = tid + i * 256;
      int ki = e & 31, m = e >> 5;
      Ws[ki][m] = w1b[(size_t)m * 128 + k0 + ki];
    }
    __syncthreads();
    for (int ki = 0; ki < 32; ki++) {
      float a = At[k0 + ki][tt];
      float w[8];
      *(float4*)&w[0] = *(const float4*)&Ws[ki][tm * 8];
      *(float4*)&w[4] = *(const float4*)&Ws[ki][tm * 8 + 4];
#pragma unroll
      for (int j = 0; j < 8; j++) acc[j] = fmaf(a, w[j], acc[j]);
    }
    __syncthreads();
  }
#pragma unroll
  for (int j = 0; j < 8; j++) {
    int f = tm * 8 + j;
    Ut[f][tt] = fmaxf(acc[j] + b1[l * 128 + f], 0.f);
    acc[j] = 0.f;
  }
  __syncthreads();
  const float* w2b = w2 + (size_t)l * 128 * 128;
  for (int k0 = 0; k0 < 128; k0 += 32) {
    for (int i = 0; i < 16; i++) {
      int e = tid + i * 256;
      int ki = e & 31, m = e >> 5;
      Ws[ki][m] = w2b[(size_t)m * 128 + k0 + ki];
    }
    __syncthreads();
    for (int ki = 0; ki < 32; ki++) {
      float a = Ut[k0 + ki][tt];
      float w[8];
      *(float4*)&w[0] = *(const float4*)&Ws[ki][tm * 8];
      *(float4*)&w[4] = *(const float4*)&Ws[ki][tm * 8 + 4];
#pragma unroll
      for (int j = 0; j < 8; j++) acc[j] = fmaf(a, w[j], acc[j]);
    }
    __syncthreads();
  }
  const float* nw = n2w + l * 128;
  const float* nb = n2b + l * 128;
  int t = t0 + tt;
  float val[8], s1 = 0.f, s2 = 0.f;
#pragma unroll
  for (int j = 0; j < 8; j++) {
    int m = tm * 8 + j;
    float v = acc[j] + b2[l * 128 + m] + At[m][tt];
    val[j] = v;
    s1 += v;
    s2 += v * v;
  }
#pragma unroll
  for (int msk = 1; msk < 16; msk <<= 1) {
    s1 += __shfl_xor(s1, msk);
    s2 += __shfl_xor(s2, msk);
  }
  float mean = s1 * (1.f / 128.f);
  float rstd = rsqrtf(s2 * (1.f / 128.f) - mean * mean + 1e-5f);
  if (t < L_SEQ) {
    float* dst = &Hout[((size_t)b * L_SEQ + t) * 128 + tm * 8];
#pragma unroll
    for (int j = 0; j < 8; j++) {
      int m = tm * 8 + j;
      dst[j] = (val[j] - mean) * rstd * nw[m] + nb[m];
    }
  }
}

// ---------------------------------------------------------------------------
// k_final: out[b,p,v] = LN(H[b,v,:]) @ proj_w.T + proj_b, v<1024.
// grid (64, 8), block 256. 16 v per block; LDS-retranspose for coalesced out.
// ---------------------------------------------------------------------------
__global__ __launch_bounds__(256) void k_final(
    const float* __restrict__ Hsrc, const float* __restrict__ fw,
    const float* __restrict__ fb, const float* __restrict__ pw,
    const float* __restrict__ pb, float* __restrict__ out) {
  int b = blockIdx.y;
  int v0 = blockIdx.x * 16;
  int tid = threadIdx.x;
  __shared__ float At[128][17];
  __shared__ float Ws[32][97];
  __shared__ float Os[96][17];
  for (int i = 0; i < 8; i++) {
    int e = tid + i * 256;
    int k = e & 127, tl = e >> 7;
    At[k][tl] = Hsrc[((size_t)b * L_SEQ + v0 + tl) * 128 + k];
  }
  __syncthreads();
  {
    int g = tid & 15, tl = tid >> 4;
    float s1 = 0.f, s2 = 0.f;
#pragma unroll
    for (int kk = 0; kk < 8; kk++) {
      float v = At[g * 8 + kk][tl];
      s1 += v;
      s2 += v * v;
    }
#pragma unroll
    for (int msk = 1; msk < 16; msk <<= 1) {
      s1 += __shfl_xor(s1, msk);
      s2 += __shfl_xor(s2, msk);
    }
    float mean = s1 * (1.f / 128.f);
    float rstd = rsqrtf(s2 * (1.f / 128.f) - mean * mean + 1e-5f);
#pragma unroll
    for (int kk = 0; kk < 8; kk++) {
      int k = g * 8 + kk;
      At[k][tl] = (At[k][tl] - mean) * rstd * fw[k] + fb[k];
    }
  }
  __syncthreads();
  int tm = tid & 15, tt = tid >> 4;
  float acc[6] = {0.f};
  for (int k0 = 0; k0 < 128; k0 += 32) {
    for (int i = 0; i < 12; i++) {
      int e = tid + i * 256;
      int ki = e & 31, p = e >> 5;
      Ws[ki][p] = pw[(size_t)p * 128 + k0 + ki];
    }
    __syncthreads();
    for (int ki = 0; ki < 32; ki++) {
      float a = At[k0 + ki][tt];
#pragma unroll
      for (int j = 0; j < 6; j++)
        acc[j] = fmaf(a, Ws[ki][tm + j * 16], acc[j]);
    }
    __syncthreads();
  }
#pragma unroll
  for (int j = 0; j < 6; j++) {
    int p = tm + j * 16;
    Os[p][tt] = acc[j] + pb[p];
  }
  __syncthreads();
  for (int i = 0; i < 6; i++) {
    int e = tid + i * 256;
    int vi = e & 15, p = e >> 4;
    out[((size_t)b * 96 + p) * 1024 + v0 + vi] = Os[p][vi];
  }
}

// ---------------------------------------------------------------------------
extern "C" void kernel_launch(void* const* d_in, const int* in_sizes, int n_in,
                              void* d_out, int out_size, void* d_ws, size_t ws_size,
                              hipStream_t stream) {
  (void)in_sizes; (void)n_in; (void)out_size; (void)ws_size;
  const float* x_enc  = (const float*)d_in[0];
  const float* x_mark = (const float*)d_in[1];
  const float* emb_w  = (const float*)d_in[4];
  const float* emb_b  = (const float*)d_in[5];
  const float* ipw    = (const float*)d_in[6];
  const float* cw     = (const float*)d_in[7];
  const float* cb     = (const float*)d_in[8];
  const float* xpw    = (const float*)d_in[9];
  const float* dpw    = (const float*)d_in[10];
  const float* dpb    = (const float*)d_in[11];
  const float* A_log  = (const float*)d_in[12];
  const float* Dpar   = (const float*)d_in[13];
  const float* opw    = (const float*)d_in[14];
  const float* n1w    = (const float*)d_in[15];
  const float* n1b    = (const float*)d_in[16];
  const float* n2w    = (const float*)d_in[17];
  const float* n2b    = (const float*)d_in[18];
  const float* fw1    = (const float*)d_in[19];
  const float* fb1    = (const float*)d_in[20];
  const float* fw2    = (const float*)d_in[21];
  const float* fb2    = (const float*)d_in[22];
  const float* fnw    = (const float*)d_in[23];
  const float* fnb    = (const float*)d_in[24];
  const float* pw     = (const float*)d_in[25];
  const float* pb     = (const float*)d_in[26];

  float* ws  = (float*)d_ws;
  float* H   = ws + OFF_H;
  float* H1  = ws + OFF_H1;
  float* XZ  = ws + OFF_XZ;
  float* XCT = ws + OFF_XCT;
  float* DLT = ws + OFF_DLT;
  float* BmT = ws + OFF_BMT;
  float* CmT = ws + OFF_CMT;
  float* YT  = ws + OFF_YT;

  k_embed<<<dim3(65, 8), 256, 0, stream>>>(x_enc, x_mark, emb_w, emb_b, H);
  for (int l = 0; l < 2; l++) {
    k_xz<<<dim3(33, 8, 4), 256, 0, stream>>>(H, ipw, XZ, l);
    k_mid<<<dim3(33, 8, 2), 256, 0, stream>>>(XZ, cw, cb, xpw, dpw, dpb,
                                              XCT, DLT, BmT, CmT, l);
    k_scan<<<dim3(16, 8, 2), 64, 0, stream>>>(DLT, XCT, BmT, CmT, A_log, Dpar, YT, l);
    k_out<<<dim3(65, 8), 256, 0, stream>>>(YT, XZ, H, opw, n1w, n1b, H1, l);
    k_ffn<<<dim3(65, 8), 256, 0, stream>>>(H1, fw1, fb1, fw2, fb2, n2w, n2b, H, l);
  }
  k_final<<<dim3(64, 8), 256, 0, stream>>>(H, fnw, fnb, pw, pb, (float*)d_out);
}

// Round 3
// 628.403 us; speedup vs baseline: 4.7140x; 4.7140x over previous
//
#include <hip/hip_runtime.h>
#include <math.h>

// ---------------------------------------------------------------------------
// Bidirectional Mamba encoder, fp32, round 3.
// Uniform GEMM template: 32x128 tile, BK=32, 256 threads, per-thread
// 2 rows x (4+4) cols (cols tm*4 and 64+tm*4 -> conflict-free b128 LDS reads).
// All global->LDS staging is one float4 load per thread per tile (single
// vmcnt group), NO register double-buffering (round-2 spill lesson).
// silu(z) gating fused into k_scan (np==0 lane, off the h-chain).
// ---------------------------------------------------------------------------

#define L_SEQ 1031
#define LP    1032
#define BATCH 8
#define NVAR  1024
#define SEQQ  512
#define TFEAT 7

#define SZ_H    ((size_t)BATCH * L_SEQ * 128)
#define SZ_XZ   ((size_t)2 * BATCH * L_SEQ * 256)
#define SZ_DT   ((size_t)2 * BATCH * 128 * LP)
#define SZ_BC   ((size_t)2 * BATCH * 16 * LP)
#define OFF_H    ((size_t)0)
#define OFF_H1   (OFF_H + SZ_H)
#define OFF_XZ   (OFF_H1 + SZ_H)
#define OFF_XCT  (OFF_XZ + SZ_XZ)
#define OFF_DLT  (OFF_XCT + SZ_DT)
#define OFF_BMT  (OFF_DLT + SZ_DT)
#define OFF_CMT  (OFF_BMT + SZ_BC)
#define OFF_YT   (OFF_CMT + SZ_BC)

__device__ __forceinline__ float silu_f(float x) {
  return x / (1.f + __expf(-x));
}
__device__ __forceinline__ float softplus_f(float x) {
  return (x > 20.f) ? x : log1pf(__expf(x));
}

// Shared GEMM fragment helpers: tm = tid&15 (col group), tt = tid>>4 (row pair).
// acc[r][0..3] -> cols tm*4..+3 ; acc[r][4..7] -> cols 64+tm*4..+3.
#define GEMM_INNER(AS, WS, ACC)                                   \
  _Pragma("unroll")                                               \
  for (int k = 0; k < 32; k++) {                                  \
    float2 a = *(const float2*)&AS[k][tt * 2];                    \
    float4 w0 = *(const float4*)&WS[k][tm * 4];                   \
    float4 w1 = *(const float4*)&WS[k][64 + tm * 4];              \
    ACC[0][0] = fmaf(a.x, w0.x, ACC[0][0]);                       \
    ACC[0][1] = fmaf(a.x, w0.y, ACC[0][1]);                       \
    ACC[0][2] = fmaf(a.x, w0.z, ACC[0][2]);                       \
    ACC[0][3] = fmaf(a.x, w0.w, ACC[0][3]);                       \
    ACC[0][4] = fmaf(a.x, w1.x, ACC[0][4]);                       \
    ACC[0][5] = fmaf(a.x, w1.y, ACC[0][5]);                       \
    ACC[0][6] = fmaf(a.x, w1.z, ACC[0][6]);                       \
    ACC[0][7] = fmaf(a.x, w1.w, ACC[0][7]);                       \
    ACC[1][0] = fmaf(a.y, w0.x, ACC[1][0]);                       \
    ACC[1][1] = fmaf(a.y, w0.y, ACC[1][1]);                       \
    ACC[1][2] = fmaf(a.y, w0.z, ACC[1][2]);                       \
    ACC[1][3] = fmaf(a.y, w0.w, ACC[1][3]);                       \
    ACC[1][4] = fmaf(a.y, w1.x, ACC[1][4]);                       \
    ACC[1][5] = fmaf(a.y, w1.y, ACC[1][5]);                       \
    ACC[1][6] = fmaf(a.y, w1.z, ACC[1][6]);                       \
    ACC[1][7] = fmaf(a.y, w1.w, ACC[1][7]);                       \
  }

// ---------------------------------------------------------------------------
// k_embed: H[b,v,:] = token(b,v,:) @ emb_w.T + emb_b  (K = 512 over s)
// grid (33, 8), block 256.
// ---------------------------------------------------------------------------
__global__ __launch_bounds__(256) void k_embed(
    const float* __restrict__ x_enc, const float* __restrict__ x_mark,
    const float* __restrict__ emb_w, const float* __restrict__ emb_b,
    float* __restrict__ H) {
  int b = blockIdx.y;
  int v0 = blockIdx.x * 32;
  int tid = threadIdx.x;
  int tm = tid & 15, tt = tid >> 4;
  __shared__ float As[32][36];    // [s][v]
  __shared__ float Ws[32][132];   // [s][m]
  float acc[2][8] = {{0.f}};
  for (int s0 = 0; s0 < SEQQ; s0 += 32) {
    // stage A: 32 v x 32 s; one float4 (along v) per thread
    {
      int v4 = tid & 7, s = tid >> 3;
      if (v0 < NVAR) {
        float4 x = *(const float4*)&x_enc[((size_t)b * SEQQ + s0 + s) * NVAR + v0 + v4 * 4];
        if (x.x == -9999.f) x.x = -1.f;
        if (x.y == -9999.f) x.y = -1.f;
        if (x.z == -9999.f) x.z = -1.f;
        if (x.w == -9999.f) x.w = -1.f;
        As[s][v4 * 4 + 0] = x.x;
        As[s][v4 * 4 + 1] = x.y;
        As[s][v4 * 4 + 2] = x.z;
        As[s][v4 * 4 + 3] = x.w;
      } else {
#pragma unroll
        for (int u = 0; u < 4; u++) {
          int v = v0 + v4 * 4 + u;
          float val = 0.f;
          if (v < L_SEQ)
            val = x_mark[((size_t)b * SEQQ + s0 + s) * TFEAT + (v - NVAR)];
          As[s][v4 * 4 + u] = val;
        }
      }
    }
    // stage W: 128 m x 32 s; 4 float4 per thread
    for (int i = 0; i < 4; i++) {
      int e = tid + i * 256;
      int m = e >> 3, k4 = e & 7;
      float4 w = *(const float4*)&emb_w[(size_t)m * SEQQ + s0 + k4 * 4];
      Ws[k4 * 4 + 0][m] = w.x;
      Ws[k4 * 4 + 1][m] = w.y;
      Ws[k4 * 4 + 2][m] = w.z;
      Ws[k4 * 4 + 3][m] = w.w;
    }
    __syncthreads();
    GEMM_INNER(As, Ws, acc);
    __syncthreads();
  }
#pragma unroll
  for (int r = 0; r < 2; r++) {
    int v = v0 + tt * 2 + r;
    if (v < L_SEQ) {
      float* dst = &H[((size_t)b * L_SEQ + v) * 128];
      float4 o0 = make_float4(acc[r][0] + emb_b[tm * 4 + 0],
                              acc[r][1] + emb_b[tm * 4 + 1],
                              acc[r][2] + emb_b[tm * 4 + 2],
                              acc[r][3] + emb_b[tm * 4 + 3]);
      float4 o1 = make_float4(acc[r][4] + emb_b[64 + tm * 4 + 0],
                              acc[r][5] + emb_b[64 + tm * 4 + 1],
                              acc[r][6] + emb_b[64 + tm * 4 + 2],
                              acc[r][7] + emb_b[64 + tm * 4 + 3]);
      *(float4*)&dst[tm * 4] = o0;
      *(float4*)&dst[64 + tm * 4] = o1;
    }
  }
}

// ---------------------------------------------------------------------------
// k_xz: XZ[dir,b,t,nh*128:+128] = h_dir(b,t,:) @ ipw[l,dir,nh-half].T
// grid (33, 8, 4) z=(dir,nh), block 256. K=128.
// ---------------------------------------------------------------------------
__global__ __launch_bounds__(256) void k_xz(
    const float* __restrict__ H, const float* __restrict__ ipw,
    float* __restrict__ XZ, int l) {
  int b = blockIdx.y;
  int dir = blockIdx.z >> 1, nh = blockIdx.z & 1;
  int t0 = blockIdx.x * 32;
  int tid = threadIdx.x;
  int tm = tid & 15, tt = tid >> 4;
  __shared__ float As[32][36];
  __shared__ float Ws[32][132];
  float acc[2][8] = {{0.f}};
  const float* wbase = ipw + (size_t)(l * 2 + dir) * 256 * 128 + (size_t)nh * 128 * 128;
  for (int k0 = 0; k0 < 128; k0 += 32) {
    {
      int row = tid >> 3, k4 = tid & 7;
      int t = t0 + row;
      float4 hv = make_float4(0.f, 0.f, 0.f, 0.f);
      if (t < L_SEQ) {
        int st = dir ? (L_SEQ - 1 - t) : t;
        hv = *(const float4*)&H[((size_t)b * L_SEQ + st) * 128 + k0 + k4 * 4];
      }
      As[k4 * 4 + 0][row] = hv.x;
      As[k4 * 4 + 1][row] = hv.y;
      As[k4 * 4 + 2][row] = hv.z;
      As[k4 * 4 + 3][row] = hv.w;
    }
    for (int i = 0; i < 4; i++) {
      int e = tid + i * 256;
      int n = e >> 3, k4 = e & 7;
      float4 w = *(const float4*)&wbase[(size_t)n * 128 + k0 + k4 * 4];
      Ws[k4 * 4 + 0][n] = w.x;
      Ws[k4 * 4 + 1][n] = w.y;
      Ws[k4 * 4 + 2][n] = w.z;
      Ws[k4 * 4 + 3][n] = w.w;
    }
    __syncthreads();
    GEMM_INNER(As, Ws, acc);
    __syncthreads();
  }
#pragma unroll
  for (int r = 0; r < 2; r++) {
    int t = t0 + tt * 2 + r;
    if (t < L_SEQ) {
      float* dst = XZ + ((size_t)(dir * BATCH + b) * L_SEQ + t) * 256 + nh * 128;
      *(float4*)&dst[tm * 4] = *(float4*)&acc[r][0];
      *(float4*)&dst[64 + tm * 4] = *(float4*)&acc[r][4];
    }
  }
}

// ---------------------------------------------------------------------------
// k_mid: conv+silu -> xc ; dbc = xc @ xpw.T ; delta=softplus(dt@dpw.T+dpb)
// grid (33, 8, 2), block 256, 32-t tiles.  (round-2 version, proven)
// ---------------------------------------------------------------------------
__global__ __launch_bounds__(256) void k_mid(
    const float* __restrict__ XZ,
    const float* __restrict__ conv_w, const float* __restrict__ conv_b,
    const float* __restrict__ xpw,
    const float* __restrict__ dpw, const float* __restrict__ dpb,
    float* __restrict__ XCT, float* __restrict__ DLT,
    float* __restrict__ BmT, float* __restrict__ CmT, int l) {
  int b = blockIdx.y, dir = blockIdx.z;
  int t0 = blockIdx.x * 32;
  int tid = threadIdx.x;
  int pg = l * 2 + dir;
  __shared__ float xcs[32][132];
  __shared__ float xpws[40][128];
  __shared__ float dbcs[40][36];
  const float* xz = XZ + (size_t)(dir * BATCH + b) * L_SEQ * 256;

  for (int i = 0; i < 20; i++) {
    int e = tid + i * 256;
    int k = e & 127, j = e >> 7;
    xpws[j][k] = xpw[((size_t)pg * 40 + j) * 128 + k];
  }
  for (int i = 0; i < 16; i++) {
    int e = tid + i * 256;
    int d = e & 127, tl = e >> 7;
    int t = t0 + tl;
    float v = 0.f;
    if (t < L_SEQ) {
      float x1 = xz[(size_t)t * 256 + d];
      float x0 = (t > 0) ? xz[(size_t)(t - 1) * 256 + d] : 0.f;
      float c0 = conv_w[((size_t)pg * 128 + d) * 2 + 0];
      float c1 = conv_w[((size_t)pg * 128 + d) * 2 + 1];
      v = silu_f(x0 * c0 + x1 * c1 + conv_b[(size_t)pg * 128 + d]);
    }
    xcs[tl][d] = v;
  }
  __syncthreads();
  {
    int tl = tid & 31, jg = tid >> 5;
    float acc[5] = {0.f};
    const float4* xrow = (const float4*)&xcs[tl][0];
    for (int kk = 0; kk < 32; kk++) {
      float4 a = xrow[kk];
#pragma unroll
      for (int jj = 0; jj < 5; jj++) {
        float4 w = ((const float4*)&xpws[jg * 5 + jj][0])[kk];
        acc[jj] = fmaf(a.x, w.x, acc[jj]);
        acc[jj] = fmaf(a.y, w.y, acc[jj]);
        acc[jj] = fmaf(a.z, w.z, acc[jj]);
        acc[jj] = fmaf(a.w, w.w, acc[jj]);
      }
    }
#pragma unroll
    for (int jj = 0; jj < 5; jj++) dbcs[jg * 5 + jj][tl] = acc[jj];
  }
  __syncthreads();
  for (int i = 0; i < 4; i++) {
    int e = tid + i * 256;
    int tl = e & 31, r = e >> 5;
    int n = r & 15, isC = r >> 4;
    int t = t0 + tl;
    if (t < LP) {
      float v = dbcs[8 + isC * 16 + n][tl];
      float* dst = isC ? CmT : BmT;
      dst[((size_t)(dir * BATCH + b) * 16 + n) * LP + t] = v;
    }
  }
  {
    int d = tid & 127, th = tid >> 7;
    float dw[8];
#pragma unroll
    for (int k = 0; k < 8; k++) dw[k] = dpw[((size_t)pg * 128 + d) * 8 + k];
    float dbv = dpb[(size_t)pg * 128 + d];
    size_t base = ((size_t)(dir * BATCH + b) * 128 + d) * LP;
    for (int tb = th * 16; tb < th * 16 + 16; tb += 4) {
      int t = t0 + tb;
      if (t < LP) {
        float dv[4], xv[4];
#pragma unroll
        for (int u = 0; u < 4; u++) {
          int tl = tb + u;
          float a = dbv;
#pragma unroll
          for (int k = 0; k < 8; k++) a = fmaf(dbcs[k][tl], dw[k], a);
          dv[u] = softplus_f(a);
          xv[u] = xcs[tl][d];
        }
        *(float4*)(DLT + base + t) = make_float4(dv[0], dv[1], dv[2], dv[3]);
        *(float4*)(XCT + base + t) = make_float4(xv[0], xv[1], xv[2], xv[3]);
      }
    }
  }
}

// ---------------------------------------------------------------------------
// k_scan: selective scan, 8 t/iter, depth-1 prefetch (round-2 core) +
// fused y *= silu(z) on the np==0 writer lane.
// grid (16, 8, 2), block 64.
// ---------------------------------------------------------------------------
__global__ __launch_bounds__(64) void k_scan(
    const float* __restrict__ DLT, const float* __restrict__ XCT,
    const float* __restrict__ BmT, const float* __restrict__ CmT,
    const float* __restrict__ XZ,
    const float* __restrict__ A_log, const float* __restrict__ Dpar,
    float* __restrict__ YT, int l) {
  int dir = blockIdx.z, b = blockIdx.y;
  int lane = threadIdx.x;
  int np = lane & 7, ds = lane >> 3;
  int d = blockIdx.x * 8 + ds;
  int pg = l * 2 + dir;
  int n0 = np * 2;
  float A0 = -__expf(A_log[((size_t)pg * 128 + d) * 16 + n0]);
  float A1 = -__expf(A_log[((size_t)pg * 128 + d) * 16 + n0 + 1]);
  float Dv = Dpar[(size_t)pg * 128 + d];
  size_t bd = ((size_t)(dir * BATCH + b) * 128 + d) * LP;
  size_t bn = ((size_t)(dir * BATCH + b) * 16 + n0) * LP;
  const float4* dl4 = (const float4*)(DLT + bd);
  const float4* xc4 = (const float4*)(XCT + bd);
  const float4* b04 = (const float4*)(BmT + bn);
  const float4* b14 = (const float4*)(BmT + bn + LP);
  const float4* c04 = (const float4*)(CmT + bn);
  const float4* c14 = (const float4*)(CmT + bn + LP);
  const float* zbase = XZ + (size_t)(dir * BATCH + b) * L_SEQ * 256 + 128 + d;
  float4* y4 = (float4*)(YT + bd);
  float h0 = 0.f, h1 = 0.f;
  const int NC = LP / 8;   // 129
  float4 cd0 = dl4[0], cd1 = dl4[1], cx0 = xc4[0], cx1 = xc4[1];
  float4 cb00 = b04[0], cb01 = b04[1], cb10 = b14[0], cb11 = b14[1];
  float4 cc00 = c04[0], cc01 = c04[1], cc10 = c14[0], cc11 = c14[1];
  float zc[8], zn[8];
  if (np == 0) {
#pragma unroll
    for (int u = 0; u < 8; u++) zc[u] = zbase[(size_t)u * 256];
  }
#define STEP1(DL, XC, B0, B1, C0, C1, YO)                \
  {                                                      \
    float du_ = (DL) * (XC);                             \
    h0 = fmaf(__expf((DL) * A0), h0, du_ * (B0));        \
    h1 = fmaf(__expf((DL) * A1), h1, du_ * (B1));        \
    float p_ = fmaf(h1, (C1), h0 * (C0));                \
    p_ += __shfl_xor(p_, 1);                             \
    p_ += __shfl_xor(p_, 2);                             \
    p_ += __shfl_xor(p_, 4);                             \
    (YO) = fmaf(Dv, (XC), p_);                           \
  }
#define STEP4(D4, X4, B04, B14, C04, C14, Y4)                       \
  STEP1((D4).x, (X4).x, (B04).x, (B14).x, (C04).x, (C14).x, (Y4).x) \
  STEP1((D4).y, (X4).y, (B04).y, (B14).y, (C04).y, (C14).y, (Y4).y) \
  STEP1((D4).z, (X4).z, (B04).z, (B14).z, (C04).z, (C14).z, (Y4).z) \
  STEP1((D4).w, (X4).w, (B04).w, (B14).w, (C04).w, (C14).w, (Y4).w)
  for (int i = 0; i < NC; i++) {
    float4 nd0 = cd0, nd1 = cd1, nx0 = cx0, nx1 = cx1;
    float4 nb00 = cb00, nb01 = cb01, nb10 = cb10, nb11 = cb11;
    float4 nc00 = cc00, nc01 = cc01, nc10 = cc10, nc11 = cc11;
    if (i + 1 < NC) {
      int o = 2 * (i + 1);
      nd0 = dl4[o]; nd1 = dl4[o + 1]; nx0 = xc4[o]; nx1 = xc4[o + 1];
      nb00 = b04[o]; nb01 = b04[o + 1]; nb10 = b14[o]; nb11 = b14[o + 1];
      nc00 = c04[o]; nc01 = c04[o + 1]; nc10 = c14[o]; nc11 = c14[o + 1];
      if (np == 0) {
        int tb = (i + 1) * 8;
        // t up to 1031 reads the XZ pad row; lands inside workspace, value
        // only reaches the discarded YT pad column -> no guard needed.
#pragma unroll
        for (int u = 0; u < 8; u++) zn[u] = zbase[(size_t)(tb + u) * 256];
      }
    }
    float4 y0, y1;
    STEP4(cd0, cx0, cb00, cb10, cc00, cc10, y0);
    STEP4(cd1, cx1, cb01, cb11, cc01, cc11, y1);
    if (np == 0) {
      y0.x *= silu_f(zc[0]); y0.y *= silu_f(zc[1]);
      y0.z *= silu_f(zc[2]); y0.w *= silu_f(zc[3]);
      y1.x *= silu_f(zc[4]); y1.y *= silu_f(zc[5]);
      y1.z *= silu_f(zc[6]); y1.w *= silu_f(zc[7]);
      y4[2 * i] = y0;
      y4[2 * i + 1] = y1;
#pragma unroll
      for (int u = 0; u < 8; u++) zc[u] = zn[u];
    }
    cd0 = nd0; cd1 = nd1; cx0 = nx0; cx1 = nx1;
    cb00 = nb00; cb01 = nb01; cb10 = nb10; cb11 = nb11;
    cc00 = nc00; cc01 = nc01; cc10 = nc10; cc11 = nc11;
  }
#undef STEP4
#undef STEP1
}

// ---------------------------------------------------------------------------
// k_out: H1 = LN1( H + Yf@opw_f.T + Yr@opw_r.T )   (Y pre-gated by silu(z))
// grid (33, 8), block 256. Virtual K = 256 (4 fwd tiles + 4 rev tiles).
// ---------------------------------------------------------------------------
__global__ __launch_bounds__(256) void k_out(
    const float* __restrict__ YT, const float* __restrict__ Hin,
    const float* __restrict__ opw,
    const float* __restrict__ n1w, const float* __restrict__ n1b,
    float* __restrict__ H1, int l) {
  int b = blockIdx.y;
  int t0 = blockIdx.x * 32;
  int tid = threadIdx.x;
  int tm = tid & 15, tt = tid >> 4;
  __shared__ float As[32][36];
  __shared__ float Ws[32][132];
  float acc[2][8] = {{0.f}};
  for (int kt = 0; kt < 8; kt++) {
    int dirp = kt >> 2;
    int k0 = (kt & 3) * 32;
    {
      int krow = tid >> 3, t4 = tid & 7;
      size_t rowbase = ((size_t)(dirp * BATCH + b) * 128 + k0 + krow) * LP;
      if (dirp == 0) {
        // over-reads past t=1030 stay inside workspace; those rows discarded
        float4 y = *(const float4*)(YT + rowbase + t0 + t4 * 4);
        As[krow][t4 * 4 + 0] = y.x;
        As[krow][t4 * 4 + 1] = y.y;
        As[krow][t4 * 4 + 2] = y.z;
        As[krow][t4 * 4 + 3] = y.w;
      } else {
        int tg = t0 + t4 * 4;
#pragma unroll
        for (int u = 0; u < 4; u++) {
          int src = (L_SEQ - 1) - (tg + u);
          As[krow][t4 * 4 + u] = (src >= 0) ? YT[rowbase + src] : 0.f;
        }
      }
    }
    const float* wsrc = opw + (size_t)(l * 2 + dirp) * 128 * 128;
    for (int i = 0; i < 4; i++) {
      int e = tid + i * 256;
      int n = e >> 3, k4 = e & 7;
      float4 w = *(const float4*)&wsrc[(size_t)n * 128 + k0 + k4 * 4];
      Ws[k4 * 4 + 0][n] = w.x;
      Ws[k4 * 4 + 1][n] = w.y;
      Ws[k4 * 4 + 2][n] = w.z;
      Ws[k4 * 4 + 3][n] = w.w;
    }
    __syncthreads();
    GEMM_INNER(As, Ws, acc);
    __syncthreads();
  }
  const float* nw = n1w + l * 128;
  const float* nb = n1b + l * 128;
#pragma unroll
  for (int r = 0; r < 2; r++) {
    int t = t0 + tt * 2 + r;
    float4 h0 = make_float4(0.f, 0.f, 0.f, 0.f);
    float4 h1 = make_float4(0.f, 0.f, 0.f, 0.f);
    if (t < L_SEQ) {
      const float* hp = &Hin[((size_t)b * L_SEQ + t) * 128];
      h0 = *(const float4*)&hp[tm * 4];
      h1 = *(const float4*)&hp[64 + tm * 4];
    }
    float v[8];
    v[0] = acc[r][0] + h0.x; v[1] = acc[r][1] + h0.y;
    v[2] = acc[r][2] + h0.z; v[3] = acc[r][3] + h0.w;
    v[4] = acc[r][4] + h1.x; v[5] = acc[r][5] + h1.y;
    v[6] = acc[r][6] + h1.z; v[7] = acc[r][7] + h1.w;
    float s1 = 0.f, s2 = 0.f;
#pragma unroll
    for (int j = 0; j < 8; j++) { s1 += v[j]; s2 += v[j] * v[j]; }
#pragma unroll
    for (int msk = 1; msk < 16; msk <<= 1) {
      s1 += __shfl_xor(s1, msk);
      s2 += __shfl_xor(s2, msk);
    }
    float mean = s1 * (1.f / 128.f);
    float rstd = rsqrtf(s2 * (1.f / 128.f) - mean * mean + 1e-5f);
    if (t < L_SEQ) {
      float* dst = &H1[((size_t)b * L_SEQ + t) * 128];
      float4 o0 = make_float4((v[0] - mean) * rstd * nw[tm * 4 + 0] + nb[tm * 4 + 0],
                              (v[1] - mean) * rstd * nw[tm * 4 + 1] + nb[tm * 4 + 1],
                              (v[2] - mean) * rstd * nw[tm * 4 + 2] + nb[tm * 4 + 2],
                              (v[3] - mean) * rstd * nw[tm * 4 + 3] + nb[tm * 4 + 3]);
      float4 o1 = make_float4((v[4] - mean) * rstd * nw[64 + tm * 4 + 0] + nb[64 + tm * 4 + 0],
                              (v[5] - mean) * rstd * nw[64 + tm * 4 + 1] + nb[64 + tm * 4 + 1],
                              (v[6] - mean) * rstd * nw[64 + tm * 4 + 2] + nb[64 + tm * 4 + 2],
                              (v[7] - mean) * rstd * nw[64 + tm * 4 + 3] + nb[64 + tm * 4 + 3]);
      *(float4*)&dst[tm * 4] = o0;
      *(float4*)&dst[64 + tm * 4] = o1;
    }
  }
}

// ---------------------------------------------------------------------------
// k_ffn: H = LN2( h1 + relu(h1@w1.T+b1)@w2.T + b2 )
// grid (33, 8), block 256. Ut kept in LDS between the two GEMMs.
// ---------------------------------------------------------------------------
__global__ __launch_bounds__(256) void k_ffn(
    const float* __restrict__ H1, const float* __restrict__ w1,
    const float* __restrict__ b1, const float* __restrict__ w2,
    const float* __restrict__ b2, const float* __restrict__ n2w,
    const float* __restrict__ n2b, float* __restrict__ Hout, int l) {
  int b = blockIdx.y;
  int t0 = blockIdx.x * 32;
  int tid = threadIdx.x;
  int tm = tid & 15, tt = tid >> 4;
  __shared__ float As[32][36];
  __shared__ float Ws[32][132];
  __shared__ float Ut[128][36];
  float acc[2][8] = {{0.f}};
  const float* w1b = w1 + (size_t)l * 128 * 128;
  for (int k0 = 0; k0 < 128; k0 += 32) {
    {
      int row = tid >> 3, k4 = tid & 7;
      int t = t0 + row;
      float4 hv = make_float4(0.f, 0.f, 0.f, 0.f);
      if (t < L_SEQ)
        hv = *(const float4*)&H1[((size_t)b * L_SEQ + t) * 128 + k0 + k4 * 4];
      As[k4 * 4 + 0][row] = hv.x;
      As[k4 * 4 + 1][row] = hv.y;
      As[k4 * 4 + 2][row] = hv.z;
      As[k4 * 4 + 3][row] = hv.w;
    }
    for (int i = 0; i < 4; i++) {
      int e = tid + i * 256;
      int n = e >> 3, k4 = e & 7;
      float4 w = *(const float4*)&w1b[(size_t)n * 128 + k0 + k4 * 4];
      Ws[k4 * 4 + 0][n] = w.x;
      Ws[k4 * 4 + 1][n] = w.y;
      Ws[k4 * 4 + 2][n] = w.z;
      Ws[k4 * 4 + 3][n] = w.w;
    }
    __syncthreads();
    GEMM_INNER(As, Ws, acc);
    __syncthreads();
  }
  // mid: relu(+b1) -> Ut[f][t] (float2 along this thread's row pair)
#pragma unroll
  for (int j = 0; j < 4; j++) {
    int f0 = tm * 4 + j;
    int f1 = 64 + tm * 4 + j;
    float2 u0 = make_float2(fmaxf(acc[0][j] + b1[l * 128 + f0], 0.f),
                            fmaxf(acc[1][j] + b1[l * 128 + f0], 0.f));
    float2 u1 = make_float2(fmaxf(acc[0][4 + j] + b1[l * 128 + f1], 0.f),
                            fmaxf(acc[1][4 + j] + b1[l * 128 + f1], 0.f));
    *(float2*)&Ut[f0][tt * 2] = u0;
    *(float2*)&Ut[f1][tt * 2] = u1;
    acc[0][j] = 0.f; acc[1][j] = 0.f;
    acc[0][4 + j] = 0.f; acc[1][4 + j] = 0.f;
  }
  __syncthreads();
  const float* w2b = w2 + (size_t)l * 128 * 128;
  for (int k0 = 0; k0 < 128; k0 += 32) {
    for (int i = 0; i < 4; i++) {
      int e = tid + i * 256;
      int n = e >> 3, k4 = e & 7;
      float4 w = *(const float4*)&w2b[(size_t)n * 128 + k0 + k4 * 4];
      Ws[k4 * 4 + 0][n] = w.x;
      Ws[k4 * 4 + 1][n] = w.y;
      Ws[k4 * 4 + 2][n] = w.z;
      Ws[k4 * 4 + 3][n] = w.w;
    }
    __syncthreads();
#pragma unroll
    for (int k = 0; k < 32; k++) {
      float2 a = *(const float2*)&Ut[k0 + k][tt * 2];
      float4 w0 = *(const float4*)&Ws[k][tm * 4];
      float4 w1v = *(const float4*)&Ws[k][64 + tm * 4];
      acc[0][0] = fmaf(a.x, w0.x, acc[0][0]);
      acc[0][1] = fmaf(a.x, w0.y, acc[0][1]);
      acc[0][2] = fmaf(a.x, w0.z, acc[0][2]);
      acc[0][3] = fmaf(a.x, w0.w, acc[0][3]);
      acc[0][4] = fmaf(a.x, w1v.x, acc[0][4]);
      acc[0][5] = fmaf(a.x, w1v.y, acc[0][5]);
      acc[0][6] = fmaf(a.x, w1v.z, acc[0][6]);
      acc[0][7] = fmaf(a.x, w1v.w, acc[0][7]);
      acc[1][0] = fmaf(a.y, w0.x, acc[1][0]);
      acc[1][1] = fmaf(a.y, w0.y, acc[1][1]);
      acc[1][2] = fmaf(a.y, w0.z, acc[1][2]);
      acc[1][3] = fmaf(a.y, w0.w, acc[1][3]);
      acc[1][4] = fmaf(a.y, w1v.x, acc[1][4]);
      acc[1][5] = fmaf(a.y, w1v.y, acc[1][5]);
      acc[1][6] = fmaf(a.y, w1v.z, acc[1][6]);
      acc[1][7] = fmaf(a.y, w1v.w, acc[1][7]);
    }
    __syncthreads();
  }
  const float* nw = n2w + l * 128;
  const float* nb = n2b + l * 128;
#pragma unroll
  for (int r = 0; r < 2; r++) {
    int t = t0 + tt * 2 + r;
    float4 h0 = make_float4(0.f, 0.f, 0.f, 0.f);
    float4 h1 = make_float4(0.f, 0.f, 0.f, 0.f);
    if (t < L_SEQ) {
      const float* hp = &H1[((size_t)b * L_SEQ + t) * 128];
      h0 = *(const float4*)&hp[tm * 4];
      h1 = *(const float4*)&hp[64 + tm * 4];
    }
    float v[8];
    v[0] = acc[r][0] + b2[l * 128 + tm * 4 + 0] + h0.x;
    v[1] = acc[r][1] + b2[l * 128 + tm * 4 + 1] + h0.y;
    v[2] = acc[r][2] + b2[l * 128 + tm * 4 + 2] + h0.z;
    v[3] = acc[r][3] + b2[l * 128 + tm * 4 + 3] + h0.w;
    v[4] = acc[r][4] + b2[l * 128 + 64 + tm * 4 + 0] + h1.x;
    v[5] = acc[r][5] + b2[l * 128 + 64 + tm * 4 + 1] + h1.y;
    v[6] = acc[r][6] + b2[l * 128 + 64 + tm * 4 + 2] + h1.z;
    v[7] = acc[r][7] + b2[l * 128 + 64 + tm * 4 + 3] + h1.w;
    float s1 = 0.f, s2 = 0.f;
#pragma unroll
    for (int j = 0; j < 8; j++) { s1 += v[j]; s2 += v[j] * v[j]; }
#pragma unroll
    for (int msk = 1; msk < 16; msk <<= 1) {
      s1 += __shfl_xor(s1, msk);
      s2 += __shfl_xor(s2, msk);
    }
    float mean = s1 * (1.f / 128.f);
    float rstd = rsqrtf(s2 * (1.f / 128.f) - mean * mean + 1e-5f);
    if (t < L_SEQ) {
      float* dst = &Hout[((size_t)b * L_SEQ + t) * 128];
      float4 o0 = make_float4((v[0] - mean) * rstd * nw[tm * 4 + 0] + nb[tm * 4 + 0],
                              (v[1] - mean) * rstd * nw[tm * 4 + 1] + nb[tm * 4 + 1],
                              (v[2] - mean) * rstd * nw[tm * 4 + 2] + nb[tm * 4 + 2],
                              (v[3] - mean) * rstd * nw[tm * 4 + 3] + nb[tm * 4 + 3]);
      float4 o1 = make_float4((v[4] - mean) * rstd * nw[64 + tm * 4 + 0] + nb[64 + tm * 4 + 0],
                              (v[5] - mean) * rstd * nw[64 + tm * 4 + 1] + nb[64 + tm * 4 + 1],
                              (v[6] - mean) * rstd * nw[64 + tm * 4 + 2] + nb[64 + tm * 4 + 2],
                              (v[7] - mean) * rstd * nw[64 + tm * 4 + 3] + nb[64 + tm * 4 + 3]);
      *(float4*)&dst[tm * 4] = o0;
      *(float4*)&dst[64 + tm * 4] = o1;
    }
  }
}

// ---------------------------------------------------------------------------
// k_final: out[b,p,v] = LN(H[b,v,:]) @ proj_w.T + proj_b, v<1024.
// grid (64, 8), block 256.  (round-2 version, proven)
// ---------------------------------------------------------------------------
__global__ __launch_bounds__(256) void k_final(
    const float* __restrict__ Hsrc, const float* __restrict__ fw,
    const float* __restrict__ fb, const float* __restrict__ pw,
    const float* __restrict__ pb, float* __restrict__ out) {
  int b = blockIdx.y;
  int v0 = blockIdx.x * 16;
  int tid = threadIdx.x;
  __shared__ float At[128][17];
  __shared__ float Ws[32][97];
  __shared__ float Os[96][17];
  for (int i = 0; i < 8; i++) {
    int e = tid + i * 256;
    int k = e & 127, tl = e >> 7;
    At[k][tl] = Hsrc[((size_t)b * L_SEQ + v0 + tl) * 128 + k];
  }
  __syncthreads();
  {
    int g = tid & 15, tl = tid >> 4;
    float s1 = 0.f, s2 = 0.f;
#pragma unroll
    for (int kk = 0; kk < 8; kk++) {
      float v = At[g * 8 + kk][tl];
      s1 += v;
      s2 += v * v;
    }
#pragma unroll
    for (int msk = 1; msk < 16; msk <<= 1) {
      s1 += __shfl_xor(s1, msk);
      s2 += __shfl_xor(s2, msk);
    }
    float mean = s1 * (1.f / 128.f);
    float rstd = rsqrtf(s2 * (1.f / 128.f) - mean * mean + 1e-5f);
#pragma unroll
    for (int kk = 0; kk < 8; kk++) {
      int k = g * 8 + kk;
      At[k][tl] = (At[k][tl] - mean) * rstd * fw[k] + fb[k];
    }
  }
  __syncthreads();
  int tm = tid & 15, tt = tid >> 4;
  float acc[6] = {0.f};
  for (int k0 = 0; k0 < 128; k0 += 32) {
    for (int i = 0; i < 12; i++) {
      int e = tid + i * 256;
      int ki = e & 31, p = e >> 5;
      Ws[ki][p] = pw[(size_t)p * 128 + k0 + ki];
    }
    __syncthreads();
    for (int ki = 0; ki < 32; ki++) {
      float a = At[k0 + ki][tt];
#pragma unroll
      for (int j = 0; j < 6; j++)
        acc[j] = fmaf(a, Ws[ki][tm + j * 16], acc[j]);
    }
    __syncthreads();
  }
#pragma unroll
  for (int j = 0; j < 6; j++) {
    int p = tm + j * 16;
    Os[p][tt] = acc[j] + pb[p];
  }
  __syncthreads();
  for (int i = 0; i < 6; i++) {
    int e = tid + i * 256;
    int vi = e & 15, p = e >> 4;
    out[((size_t)b * 96 + p) * 1024 + v0 + vi] = Os[p][vi];
  }
}

// ---------------------------------------------------------------------------
extern "C" void kernel_launch(void* const* d_in, const int* in_sizes, int n_in,
                              void* d_out, int out_size, void* d_ws, size_t ws_size,
                              hipStream_t stream) {
  (void)in_sizes; (void)n_in; (void)out_size; (void)ws_size;
  const float* x_enc  = (const float*)d_in[0];
  const float* x_mark = (const float*)d_in[1];
  const float* emb_w  = (const float*)d_in[4];
  const float* emb_b  = (const float*)d_in[5];
  const float* ipw    = (const float*)d_in[6];
  const float* cw     = (const float*)d_in[7];
  const float* cb     = (const float*)d_in[8];
  const float* xpw    = (const float*)d_in[9];
  const float* dpw    = (const float*)d_in[10];
  const float* dpb    = (const float*)d_in[11];
  const float* A_log  = (const float*)d_in[12];
  const float* Dpar   = (const float*)d_in[13];
  const float* opw    = (const float*)d_in[14];
  const float* n1w    = (const float*)d_in[15];
  const float* n1b    = (const float*)d_in[16];
  const float* n2w    = (const float*)d_in[17];
  const float* n2b    = (const float*)d_in[18];
  const float* fw1    = (const float*)d_in[19];
  const float* fb1    = (const float*)d_in[20];
  const float* fw2    = (const float*)d_in[21];
  const float* fb2    = (const float*)d_in[22];
  const float* fnw    = (const float*)d_in[23];
  const float* fnb    = (const float*)d_in[24];
  const float* pw     = (const float*)d_in[25];
  const float* pb     = (const float*)d_in[26];

  float* ws  = (float*)d_ws;
  float* H   = ws + OFF_H;
  float* H1  = ws + OFF_H1;
  float* XZ  = ws + OFF_XZ;
  float* XCT = ws + OFF_XCT;
  float* DLT = ws + OFF_DLT;
  float* BmT = ws + OFF_BMT;
  float* CmT = ws + OFF_CMT;
  float* YT  = ws + OFF_YT;

  k_embed<<<dim3(33, 8), 256, 0, stream>>>(x_enc, x_mark, emb_w, emb_b, H);
  for (int l = 0; l < 2; l++) {
    k_xz<<<dim3(33, 8, 4), 256, 0, stream>>>(H, ipw, XZ, l);
    k_mid<<<dim3(33, 8, 2), 256, 0, stream>>>(XZ, cw, cb, xpw, dpw, dpb,
                                              XCT, DLT, BmT, CmT, l);
    k_scan<<<dim3(16, 8, 2), 64, 0, stream>>>(DLT, XCT, BmT, CmT, XZ,
                                              A_log, Dpar, YT, l);
    k_out<<<dim3(33, 8), 256, 0, stream>>>(YT, H, opw, n1w, n1b, H1, l);
    k_ffn<<<dim3(33, 8), 256, 0, stream>>>(H1, fw1, fb1, fw2, fb2, n2w, n2b, H, l);
  }
  k_final<<<dim3(64, 8), 256, 0, stream>>>(H, fnw, fnb, pw, pb, (float*)d_out);
}

// Round 4
// 487.389 us; speedup vs baseline: 6.0779x; 1.2893x over previous
//
#include <hip/hip_runtime.h>
#include <math.h>

// ---------------------------------------------------------------------------
// Bidirectional Mamba encoder, fp32, round 4.
// Round-3 GEMM structure kept. Selective scan replaced by a two-pass chunked
// scan (C=8 chunks of TC=132): pass 1 computes per-chunk decay product P and
// end-state h_end; pass 2 rebuilds each chunk's init from the summaries and
// re-runs the chunk writing gated y. 8x t-parallelism -> 8 waves/CU.
// Summary buffers overlay the H1 region (unused during the scan).
// ---------------------------------------------------------------------------

#define L_SEQ 1031
#define LP    1056          // 8 chunks x 132
#define TC    132
#define NCH   8
#define BATCH 8
#define NVAR  1024
#define SEQQ  512
#define TFEAT 7

#define SZ_H    ((size_t)BATCH * L_SEQ * 128)
#define SZ_XZ   ((size_t)2 * BATCH * L_SEQ * 256)
#define SZ_DT   ((size_t)2 * BATCH * 128 * LP)
#define SZ_BC   ((size_t)2 * BATCH * 16 * LP)
#define OFF_H    ((size_t)0)
#define OFF_H1   (OFF_H + SZ_H)
#define OFF_XZ   (OFF_H1 + SZ_H)
#define OFF_XCT  (OFF_XZ + SZ_XZ)
#define OFF_DLT  (OFF_XCT + SZ_DT)
#define OFF_BMT  (OFF_DLT + SZ_DT)
#define OFF_CMT  (OFF_BMT + SZ_BC)
#define OFF_YT   (OFF_CMT + SZ_BC)
// chunk summaries overlay H1 (H1 = 1,055,744 floats >= 2 * 262,144):
#define SZ_SUM  ((size_t)2 * BATCH * NCH * 128 * 16)   // 262,144 floats

__device__ __forceinline__ float silu_f(float x) {
  return x / (1.f + __expf(-x));
}
__device__ __forceinline__ float softplus_f(float x) {
  return (x > 20.f) ? x : log1pf(__expf(x));
}

#define GEMM_INNER(AS, WS, ACC)                                   \
  _Pragma("unroll")                                               \
  for (int k = 0; k < 32; k++) {                                  \
    float2 a = *(const float2*)&AS[k][tt * 2];                    \
    float4 w0 = *(const float4*)&WS[k][tm * 4];                   \
    float4 w1 = *(const float4*)&WS[k][64 + tm * 4];              \
    ACC[0][0] = fmaf(a.x, w0.x, ACC[0][0]);                       \
    ACC[0][1] = fmaf(a.x, w0.y, ACC[0][1]);                       \
    ACC[0][2] = fmaf(a.x, w0.z, ACC[0][2]);                       \
    ACC[0][3] = fmaf(a.x, w0.w, ACC[0][3]);                       \
    ACC[0][4] = fmaf(a.x, w1.x, ACC[0][4]);                       \
    ACC[0][5] = fmaf(a.x, w1.y, ACC[0][5]);                       \
    ACC[0][6] = fmaf(a.x, w1.z, ACC[0][6]);                       \
    ACC[0][7] = fmaf(a.x, w1.w, ACC[0][7]);                       \
    ACC[1][0] = fmaf(a.y, w0.x, ACC[1][0]);                       \
    ACC[1][1] = fmaf(a.y, w0.y, ACC[1][1]);                       \
    ACC[1][2] = fmaf(a.y, w0.z, ACC[1][2]);                       \
    ACC[1][3] = fmaf(a.y, w0.w, ACC[1][3]);                       \
    ACC[1][4] = fmaf(a.y, w1.x, ACC[1][4]);                       \
    ACC[1][5] = fmaf(a.y, w1.y, ACC[1][5]);                       \
    ACC[1][6] = fmaf(a.y, w1.z, ACC[1][6]);                       \
    ACC[1][7] = fmaf(a.y, w1.w, ACC[1][7]);                       \
  }

// ---------------------------------------------------------------------------
// k_embed: H[b,v,:] = token(b,v,:) @ emb_w.T + emb_b   (round-3, proven)
// ---------------------------------------------------------------------------
__global__ __launch_bounds__(256) void k_embed(
    const float* __restrict__ x_enc, const float* __restrict__ x_mark,
    const float* __restrict__ emb_w, const float* __restrict__ emb_b,
    float* __restrict__ H) {
  int b = blockIdx.y;
  int v0 = blockIdx.x * 32;
  int tid = threadIdx.x;
  int tm = tid & 15, tt = tid >> 4;
  __shared__ float As[32][36];
  __shared__ float Ws[32][132];
  float acc[2][8] = {{0.f}};
  for (int s0 = 0; s0 < SEQQ; s0 += 32) {
    {
      int v4 = tid & 7, s = tid >> 3;
      if (v0 < NVAR) {
        float4 x = *(const float4*)&x_enc[((size_t)b * SEQQ + s0 + s) * NVAR + v0 + v4 * 4];
        if (x.x == -9999.f) x.x = -1.f;
        if (x.y == -9999.f) x.y = -1.f;
        if (x.z == -9999.f) x.z = -1.f;
        if (x.w == -9999.f) x.w = -1.f;
        As[s][v4 * 4 + 0] = x.x;
        As[s][v4 * 4 + 1] = x.y;
        As[s][v4 * 4 + 2] = x.z;
        As[s][v4 * 4 + 3] = x.w;
      } else {
#pragma unroll
        for (int u = 0; u < 4; u++) {
          int v = v0 + v4 * 4 + u;
          float val = 0.f;
          if (v < L_SEQ)
            val = x_mark[((size_t)b * SEQQ + s0 + s) * TFEAT + (v - NVAR)];
          As[s][v4 * 4 + u] = val;
        }
      }
    }
    for (int i = 0; i < 4; i++) {
      int e = tid + i * 256;
      int m = e >> 3, k4 = e & 7;
      float4 w = *(const float4*)&emb_w[(size_t)m * SEQQ + s0 + k4 * 4];
      Ws[k4 * 4 + 0][m] = w.x;
      Ws[k4 * 4 + 1][m] = w.y;
      Ws[k4 * 4 + 2][m] = w.z;
      Ws[k4 * 4 + 3][m] = w.w;
    }
    __syncthreads();
    GEMM_INNER(As, Ws, acc);
    __syncthreads();
  }
#pragma unroll
  for (int r = 0; r < 2; r++) {
    int v = v0 + tt * 2 + r;
    if (v < L_SEQ) {
      float* dst = &H[((size_t)b * L_SEQ + v) * 128];
      float4 o0 = make_float4(acc[r][0] + emb_b[tm * 4 + 0],
                              acc[r][1] + emb_b[tm * 4 + 1],
                              acc[r][2] + emb_b[tm * 4 + 2],
                              acc[r][3] + emb_b[tm * 4 + 3]);
      float4 o1 = make_float4(acc[r][4] + emb_b[64 + tm * 4 + 0],
                              acc[r][5] + emb_b[64 + tm * 4 + 1],
                              acc[r][6] + emb_b[64 + tm * 4 + 2],
                              acc[r][7] + emb_b[64 + tm * 4 + 3]);
      *(float4*)&dst[tm * 4] = o0;
      *(float4*)&dst[64 + tm * 4] = o1;
    }
  }
}

// ---------------------------------------------------------------------------
// k_xz  (round-3, proven)
// ---------------------------------------------------------------------------
__global__ __launch_bounds__(256) void k_xz(
    const float* __restrict__ H, const float* __restrict__ ipw,
    float* __restrict__ XZ, int l) {
  int b = blockIdx.y;
  int dir = blockIdx.z >> 1, nh = blockIdx.z & 1;
  int t0 = blockIdx.x * 32;
  int tid = threadIdx.x;
  int tm = tid & 15, tt = tid >> 4;
  __shared__ float As[32][36];
  __shared__ float Ws[32][132];
  float acc[2][8] = {{0.f}};
  const float* wbase = ipw + (size_t)(l * 2 + dir) * 256 * 128 + (size_t)nh * 128 * 128;
  for (int k0 = 0; k0 < 128; k0 += 32) {
    {
      int row = tid >> 3, k4 = tid & 7;
      int t = t0 + row;
      float4 hv = make_float4(0.f, 0.f, 0.f, 0.f);
      if (t < L_SEQ) {
        int st = dir ? (L_SEQ - 1 - t) : t;
        hv = *(const float4*)&H[((size_t)b * L_SEQ + st) * 128 + k0 + k4 * 4];
      }
      As[k4 * 4 + 0][row] = hv.x;
      As[k4 * 4 + 1][row] = hv.y;
      As[k4 * 4 + 2][row] = hv.z;
      As[k4 * 4 + 3][row] = hv.w;
    }
    for (int i = 0; i < 4; i++) {
      int e = tid + i * 256;
      int n = e >> 3, k4 = e & 7;
      float4 w = *(const float4*)&wbase[(size_t)n * 128 + k0 + k4 * 4];
      Ws[k4 * 4 + 0][n] = w.x;
      Ws[k4 * 4 + 1][n] = w.y;
      Ws[k4 * 4 + 2][n] = w.z;
      Ws[k4 * 4 + 3][n] = w.w;
    }
    __syncthreads();
    GEMM_INNER(As, Ws, acc);
    __syncthreads();
  }
#pragma unroll
  for (int r = 0; r < 2; r++) {
    int t = t0 + tt * 2 + r;
    if (t < L_SEQ) {
      float* dst = XZ + ((size_t)(dir * BATCH + b) * L_SEQ + t) * 256 + nh * 128;
      *(float4*)&dst[tm * 4] = *(float4*)&acc[r][0];
      *(float4*)&dst[64 + tm * 4] = *(float4*)&acc[r][4];
    }
  }
}

// ---------------------------------------------------------------------------
// k_mid  (round-3, proven; covers t < LP = 1056 exactly with 33 blocks)
// ---------------------------------------------------------------------------
__global__ __launch_bounds__(256) void k_mid(
    const float* __restrict__ XZ,
    const float* __restrict__ conv_w, const float* __restrict__ conv_b,
    const float* __restrict__ xpw,
    const float* __restrict__ dpw, const float* __restrict__ dpb,
    float* __restrict__ XCT, float* __restrict__ DLT,
    float* __restrict__ BmT, float* __restrict__ CmT, int l) {
  int b = blockIdx.y, dir = blockIdx.z;
  int t0 = blockIdx.x * 32;
  int tid = threadIdx.x;
  int pg = l * 2 + dir;
  __shared__ float xcs[32][132];
  __shared__ float xpws[40][128];
  __shared__ float dbcs[40][36];
  const float* xz = XZ + (size_t)(dir * BATCH + b) * L_SEQ * 256;

  for (int i = 0; i < 20; i++) {
    int e = tid + i * 256;
    int k = e & 127, j = e >> 7;
    xpws[j][k] = xpw[((size_t)pg * 40 + j) * 128 + k];
  }
  for (int i = 0; i < 16; i++) {
    int e = tid + i * 256;
    int d = e & 127, tl = e >> 7;
    int t = t0 + tl;
    float v = 0.f;
    if (t < L_SEQ) {
      float x1 = xz[(size_t)t * 256 + d];
      float x0 = (t > 0) ? xz[(size_t)(t - 1) * 256 + d] : 0.f;
      float c0 = conv_w[((size_t)pg * 128 + d) * 2 + 0];
      float c1 = conv_w[((size_t)pg * 128 + d) * 2 + 1];
      v = silu_f(x0 * c0 + x1 * c1 + conv_b[(size_t)pg * 128 + d]);
    }
    xcs[tl][d] = v;
  }
  __syncthreads();
  {
    int tl = tid & 31, jg = tid >> 5;
    float acc[5] = {0.f};
    const float4* xrow = (const float4*)&xcs[tl][0];
    for (int kk = 0; kk < 32; kk++) {
      float4 a = xrow[kk];
#pragma unroll
      for (int jj = 0; jj < 5; jj++) {
        float4 w = ((const float4*)&xpws[jg * 5 + jj][0])[kk];
        acc[jj] = fmaf(a.x, w.x, acc[jj]);
        acc[jj] = fmaf(a.y, w.y, acc[jj]);
        acc[jj] = fmaf(a.z, w.z, acc[jj]);
        acc[jj] = fmaf(a.w, w.w, acc[jj]);
      }
    }
#pragma unroll
    for (int jj = 0; jj < 5; jj++) dbcs[jg * 5 + jj][tl] = acc[jj];
  }
  __syncthreads();
  for (int i = 0; i < 4; i++) {
    int e = tid + i * 256;
    int tl = e & 31, r = e >> 5;
    int n = r & 15, isC = r >> 4;
    int t = t0 + tl;
    if (t < LP) {
      float v = dbcs[8 + isC * 16 + n][tl];
      float* dst = isC ? CmT : BmT;
      dst[((size_t)(dir * BATCH + b) * 16 + n) * LP + t] = v;
    }
  }
  {
    int d = tid & 127, th = tid >> 7;
    float dw[8];
#pragma unroll
    for (int k = 0; k < 8; k++) dw[k] = dpw[((size_t)pg * 128 + d) * 8 + k];
    float dbv = dpb[(size_t)pg * 128 + d];
    size_t base = ((size_t)(dir * BATCH + b) * 128 + d) * LP;
    for (int tb = th * 16; tb < th * 16 + 16; tb += 4) {
      int t = t0 + tb;
      if (t < LP) {
        float dv[4], xv[4];
#pragma unroll
        for (int u = 0; u < 4; u++) {
          int tl = tb + u;
          float a = dbv;
#pragma unroll
          for (int k = 0; k < 8; k++) a = fmaf(dbcs[k][tl], dw[k], a);
          dv[u] = softplus_f(a);
          xv[u] = xcs[tl][d];
        }
        *(float4*)(DLT + base + t) = make_float4(dv[0], dv[1], dv[2], dv[3]);
        *(float4*)(XCT + base + t) = make_float4(xv[0], xv[1], xv[2], xv[3]);
      }
    }
  }
}

// ---------------------------------------------------------------------------
// k_scan1: pass 1 of chunked scan. Per (dir,b,chunk,d,n-pair): run local
// recurrence from h=0 over TC=132 steps; write decay product P and end
// state h_end to the summary buffers. grid (16, 8, 16) z=(dir,chunk), blk 64.
// ---------------------------------------------------------------------------
__global__ __launch_bounds__(64) void k_scan1(
    const float* __restrict__ DLT, const float* __restrict__ XCT,
    const float* __restrict__ BmT,
    const float* __restrict__ A_log,
    float* __restrict__ sumH, float* __restrict__ sumP, int l) {
  int z = blockIdx.z;
  int dir = z >> 3, j = z & 7;
  int b = blockIdx.y;
  int lane = threadIdx.x;
  int np = lane & 7, ds = lane >> 3;
  int d = blockIdx.x * 8 + ds;
  int pg = l * 2 + dir;
  int n0 = np * 2;
  float A0 = -__expf(A_log[((size_t)pg * 128 + d) * 16 + n0]);
  float A1 = -__expf(A_log[((size_t)pg * 128 + d) * 16 + n0 + 1]);
  size_t bd = ((size_t)(dir * BATCH + b) * 128 + d) * LP + (size_t)j * TC;
  size_t bn = ((size_t)(dir * BATCH + b) * 16 + n0) * LP + (size_t)j * TC;
  const float4* dl4 = (const float4*)(DLT + bd);
  const float4* xc4 = (const float4*)(XCT + bd);
  const float4* b04 = (const float4*)(BmT + bn);
  const float4* b14 = (const float4*)(BmT + bn + LP);
  float h0 = 0.f, h1 = 0.f, P0 = 1.f, P1 = 1.f;
  const int NI = TC / 4;   // 33
  float4 cd = dl4[0], cx = xc4[0], cb0 = b04[0], cb1 = b14[0];
#define P1STEP(DL, XC, B0, B1)                       \
  {                                                  \
    float a0_ = __expf((DL) * A0);                   \
    float a1_ = __expf((DL) * A1);                   \
    float du_ = (DL) * (XC);                         \
    h0 = fmaf(a0_, h0, du_ * (B0));                  \
    h1 = fmaf(a1_, h1, du_ * (B1));                  \
    P0 *= a0_;                                       \
    P1 *= a1_;                                       \
  }
  for (int i = 0; i < NI; i++) {
    float4 nd = cd, nx = cx, nb0 = cb0, nb1 = cb1;
    if (i + 1 < NI) {
      nd = dl4[i + 1]; nx = xc4[i + 1];
      nb0 = b04[i + 1]; nb1 = b14[i + 1];
    }
    P1STEP(cd.x, cx.x, cb0.x, cb1.x);
    P1STEP(cd.y, cx.y, cb0.y, cb1.y);
    P1STEP(cd.z, cx.z, cb0.z, cb1.z);
    P1STEP(cd.w, cx.w, cb0.w, cb1.w);
    cd = nd; cx = nx; cb0 = nb0; cb1 = nb1;
  }
#undef P1STEP
  size_t si = (((size_t)(dir * BATCH + b) * NCH + j) * 128 + d) * 16 + n0;
  *(float2*)&sumH[si] = make_float2(h0, h1);
  *(float2*)&sumP[si] = make_float2(P0, P1);
}

// ---------------------------------------------------------------------------
// k_scan2: pass 2. Rebuild chunk init from summaries (<=7 fma), re-run the
// chunk computing y, gate with silu(z) on the writer lane, write YT.
// grid (16, 8, 16) z=(dir,chunk), block 64.
// ---------------------------------------------------------------------------
__global__ __launch_bounds__(64) void k_scan2(
    const float* __restrict__ DLT, const float* __restrict__ XCT,
    const float* __restrict__ BmT, const float* __restrict__ CmT,
    const float* __restrict__ XZ,
    const float* __restrict__ A_log, const float* __restrict__ Dpar,
    const float* __restrict__ sumH, const float* __restrict__ sumP,
    float* __restrict__ YT, int l) {
  int z = blockIdx.z;
  int dir = z >> 3, j = z & 7;
  int b = blockIdx.y;
  int lane = threadIdx.x;
  int np = lane & 7, ds = lane >> 3;
  int d = blockIdx.x * 8 + ds;
  int pg = l * 2 + dir;
  int n0 = np * 2;
  float A0 = -__expf(A_log[((size_t)pg * 128 + d) * 16 + n0]);
  float A1 = -__expf(A_log[((size_t)pg * 128 + d) * 16 + n0 + 1]);
  float Dv = Dpar[(size_t)pg * 128 + d];
  // rebuild init state from chunk summaries 0..j-1
  float h0 = 0.f, h1 = 0.f;
  {
    size_t sbase = ((size_t)(dir * BATCH + b) * NCH) * 2048 + (size_t)d * 16 + n0;
    for (int jj = 0; jj < j; jj++) {
      float2 hE = *(const float2*)&sumH[sbase + (size_t)jj * 2048];
      float2 Pp = *(const float2*)&sumP[sbase + (size_t)jj * 2048];
      h0 = fmaf(Pp.x, h0, hE.x);
      h1 = fmaf(Pp.y, h1, hE.y);
    }
  }
  size_t bd = ((size_t)(dir * BATCH + b) * 128 + d) * LP + (size_t)j * TC;
  size_t bn = ((size_t)(dir * BATCH + b) * 16 + n0) * LP + (size_t)j * TC;
  const float4* dl4 = (const float4*)(DLT + bd);
  const float4* xc4 = (const float4*)(XCT + bd);
  const float4* b04 = (const float4*)(BmT + bn);
  const float4* b14 = (const float4*)(BmT + bn + LP);
  const float4* c04 = (const float4*)(CmT + bn);
  const float4* c14 = (const float4*)(CmT + bn + LP);
  const float* zbase = XZ + (size_t)(dir * BATCH + b) * L_SEQ * 256 + 128 + d
                       + (size_t)j * TC * 256;
  float4* y4 = (float4*)(YT + bd);
  const int NI = TC / 4;   // 33
  float4 cd = dl4[0], cx = xc4[0], cb0 = b04[0], cb1 = b14[0];
  float4 cc0 = c04[0], cc1 = c14[0];
  float zc[4], zn[4];
  if (np == 0) {
#pragma unroll
    for (int u = 0; u < 4; u++) zc[u] = zbase[(size_t)u * 256];
  }
#define STEP1(DL, XC, B0, B1, C0, C1, YO)            \
  {                                                  \
    float du_ = (DL) * (XC);                         \
    h0 = fmaf(__expf((DL) * A0), h0, du_ * (B0));    \
    h1 = fmaf(__expf((DL) * A1), h1, du_ * (B1));    \
    float p_ = fmaf(h1, (C1), h0 * (C0));            \
    p_ += __shfl_xor(p_, 1);                         \
    p_ += __shfl_xor(p_, 2);                         \
    p_ += __shfl_xor(p_, 4);                         \
    (YO) = fmaf(Dv, (XC), p_);                       \
  }
  for (int i = 0; i < NI; i++) {
    float4 nd = cd, nx = cx, nb0 = cb0, nb1 = cb1, nc0 = cc0, nc1 = cc1;
    if (i + 1 < NI) {
      nd = dl4[i + 1]; nx = xc4[i + 1];
      nb0 = b04[i + 1]; nb1 = b14[i + 1];
      nc0 = c04[i + 1]; nc1 = c14[i + 1];
      if (np == 0) {
        int tb = (i + 1) * 4;
        // reads past the XZ slice for pad t land in XCT (finite floats);
        // the gated value multiplies y==0 there and the column is discarded.
#pragma unroll
        for (int u = 0; u < 4; u++) zn[u] = zbase[(size_t)(tb + u) * 256];
      }
    }
    float4 y;
    STEP1(cd.x, cx.x, cb0.x, cb1.x, cc0.x, cc1.x, y.x);
    STEP1(cd.y, cx.y, cb0.y, cb1.y, cc0.y, cc1.y, y.y);
    STEP1(cd.z, cx.z, cb0.z, cb1.z, cc0.z, cc1.z, y.z);
    STEP1(cd.w, cx.w, cb0.w, cb1.w, cc0.w, cc1.w, y.w);
    if (np == 0) {
      y.x *= silu_f(zc[0]);
      y.y *= silu_f(zc[1]);
      y.z *= silu_f(zc[2]);
      y.w *= silu_f(zc[3]);
      y4[i] = y;
#pragma unroll
      for (int u = 0; u < 4; u++) zc[u] = zn[u];
    }
    cd = nd; cx = nx; cb0 = nb0; cb1 = nb1; cc0 = nc0; cc1 = nc1;
  }
#undef STEP1
}

// ---------------------------------------------------------------------------
// k_out  (round-3, proven; LP updated via macro)
// ---------------------------------------------------------------------------
__global__ __launch_bounds__(256) void k_out(
    const float* __restrict__ YT, const float* __restrict__ Hin,
    const float* __restrict__ opw,
    const float* __restrict__ n1w, const float* __restrict__ n1b,
    float* __restrict__ H1, int l) {
  int b = blockIdx.y;
  int t0 = blockIdx.x * 32;
  int tid = threadIdx.x;
  int tm = tid & 15, tt = tid >> 4;
  __shared__ float As[32][36];
  __shared__ float Ws[32][132];
  float acc[2][8] = {{0.f}};
  for (int kt = 0; kt < 8; kt++) {
    int dirp = kt >> 2;
    int k0 = (kt & 3) * 32;
    {
      int krow = tid >> 3, t4 = tid & 7;
      size_t rowbase = ((size_t)(dirp * BATCH + b) * 128 + k0 + krow) * LP;
      if (dirp == 0) {
        float4 y = *(const float4*)(YT + rowbase + t0 + t4 * 4);
        As[krow][t4 * 4 + 0] = y.x;
        As[krow][t4 * 4 + 1] = y.y;
        As[krow][t4 * 4 + 2] = y.z;
        As[krow][t4 * 4 + 3] = y.w;
      } else {
        int tg = t0 + t4 * 4;
#pragma unroll
        for (int u = 0; u < 4; u++) {
          int src = (L_SEQ - 1) - (tg + u);
          As[krow][t4 * 4 + u] = (src >= 0) ? YT[rowbase + src] : 0.f;
        }
      }
    }
    const float* wsrc = opw + (size_t)(l * 2 + dirp) * 128 * 128;
    for (int i = 0; i < 4; i++) {
      int e = tid + i * 256;
      int n = e >> 3, k4 = e & 7;
      float4 w = *(const float4*)&wsrc[(size_t)n * 128 + k0 + k4 * 4];
      Ws[k4 * 4 + 0][n] = w.x;
      Ws[k4 * 4 + 1][n] = w.y;
      Ws[k4 * 4 + 2][n] = w.z;
      Ws[k4 * 4 + 3][n] = w.w;
    }
    __syncthreads();
    GEMM_INNER(As, Ws, acc);
    __syncthreads();
  }
  const float* nw = n1w + l * 128;
  const float* nb = n1b + l * 128;
#pragma unroll
  for (int r = 0; r < 2; r++) {
    int t = t0 + tt * 2 + r;
    float4 h0 = make_float4(0.f, 0.f, 0.f, 0.f);
    float4 h1 = make_float4(0.f, 0.f, 0.f, 0.f);
    if (t < L_SEQ) {
      const float* hp = &Hin[((size_t)b * L_SEQ + t) * 128];
      h0 = *(const float4*)&hp[tm * 4];
      h1 = *(const float4*)&hp[64 + tm * 4];
    }
    float v[8];
    v[0] = acc[r][0] + h0.x; v[1] = acc[r][1] + h0.y;
    v[2] = acc[r][2] + h0.z; v[3] = acc[r][3] + h0.w;
    v[4] = acc[r][4] + h1.x; v[5] = acc[r][5] + h1.y;
    v[6] = acc[r][6] + h1.z; v[7] = acc[r][7] + h1.w;
    float s1 = 0.f, s2 = 0.f;
#pragma unroll
    for (int jq = 0; jq < 8; jq++) { s1 += v[jq]; s2 += v[jq] * v[jq]; }
#pragma unroll
    for (int msk = 1; msk < 16; msk <<= 1) {
      s1 += __shfl_xor(s1, msk);
      s2 += __shfl_xor(s2, msk);
    }
    float mean = s1 * (1.f / 128.f);
    float rstd = rsqrtf(s2 * (1.f / 128.f) - mean * mean + 1e-5f);
    if (t < L_SEQ) {
      float* dst = &H1[((size_t)b * L_SEQ + t) * 128];
      float4 o0 = make_float4((v[0] - mean) * rstd * nw[tm * 4 + 0] + nb[tm * 4 + 0],
                              (v[1] - mean) * rstd * nw[tm * 4 + 1] + nb[tm * 4 + 1],
                              (v[2] - mean) * rstd * nw[tm * 4 + 2] + nb[tm * 4 + 2],
                              (v[3] - mean) * rstd * nw[tm * 4 + 3] + nb[tm * 4 + 3]);
      float4 o1 = make_float4((v[4] - mean) * rstd * nw[64 + tm * 4 + 0] + nb[64 + tm * 4 + 0],
                              (v[5] - mean) * rstd * nw[64 + tm * 4 + 1] + nb[64 + tm * 4 + 1],
                              (v[6] - mean) * rstd * nw[64 + tm * 4 + 2] + nb[64 + tm * 4 + 2],
                              (v[7] - mean) * rstd * nw[64 + tm * 4 + 3] + nb[64 + tm * 4 + 3]);
      *(float4*)&dst[tm * 4] = o0;
      *(float4*)&dst[64 + tm * 4] = o1;
    }
  }
}

// ---------------------------------------------------------------------------
// k_ffn  (round-3, proven)
// ---------------------------------------------------------------------------
__global__ __launch_bounds__(256) void k_ffn(
    const float* __restrict__ H1, const float* __restrict__ w1,
    const float* __restrict__ b1, const float* __restrict__ w2,
    const float* __restrict__ b2, const float* __restrict__ n2w,
    const float* __restrict__ n2b, float* __restrict__ Hout, int l) {
  int b = blockIdx.y;
  int t0 = blockIdx.x * 32;
  int tid = threadIdx.x;
  int tm = tid & 15, tt = tid >> 4;
  __shared__ float As[32][36];
  __shared__ float Ws[32][132];
  __shared__ float Ut[128][36];
  float acc[2][8] = {{0.f}};
  const float* w1b = w1 + (size_t)l * 128 * 128;
  for (int k0 = 0; k0 < 128; k0 += 32) {
    {
      int row = tid >> 3, k4 = tid & 7;
      int t = t0 + row;
      float4 hv = make_float4(0.f, 0.f, 0.f, 0.f);
      if (t < L_SEQ)
        hv = *(const float4*)&H1[((size_t)b * L_SEQ + t) * 128 + k0 + k4 * 4];
      As[k4 * 4 + 0][row] = hv.x;
      As[k4 * 4 + 1][row] = hv.y;
      As[k4 * 4 + 2][row] = hv.z;
      As[k4 * 4 + 3][row] = hv.w;
    }
    for (int i = 0; i < 4; i++) {
      int e = tid + i * 256;
      int n = e >> 3, k4 = e & 7;
      float4 w = *(const float4*)&w1b[(size_t)n * 128 + k0 + k4 * 4];
      Ws[k4 * 4 + 0][n] = w.x;
      Ws[k4 * 4 + 1][n] = w.y;
      Ws[k4 * 4 + 2][n] = w.z;
      Ws[k4 * 4 + 3][n] = w.w;
    }
    __syncthreads();
    GEMM_INNER(As, Ws, acc);
    __syncthreads();
  }
#pragma unroll
  for (int jq = 0; jq < 4; jq++) {
    int f0 = tm * 4 + jq;
    int f1 = 64 + tm * 4 + jq;
    float2 u0 = make_float2(fmaxf(acc[0][jq] + b1[l * 128 + f0], 0.f),
                            fmaxf(acc[1][jq] + b1[l * 128 + f0], 0.f));
    float2 u1 = make_float2(fmaxf(acc[0][4 + jq] + b1[l * 128 + f1], 0.f),
                            fmaxf(acc[1][4 + jq] + b1[l * 128 + f1], 0.f));
    *(float2*)&Ut[f0][tt * 2] = u0;
    *(float2*)&Ut[f1][tt * 2] = u1;
    acc[0][jq] = 0.f; acc[1][jq] = 0.f;
    acc[0][4 + jq] = 0.f; acc[1][4 + jq] = 0.f;
  }
  __syncthreads();
  const float* w2b = w2 + (size_t)l * 128 * 128;
  for (int k0 = 0; k0 < 128; k0 += 32) {
    for (int i = 0; i < 4; i++) {
      int e = tid + i * 256;
      int n = e >> 3, k4 = e & 7;
      float4 w = *(const float4*)&w2b[(size_t)n * 128 + k0 + k4 * 4];
      Ws[k4 * 4 + 0][n] = w.x;
      Ws[k4 * 4 + 1][n] = w.y;
      Ws[k4 * 4 + 2][n] = w.z;
      Ws[k4 * 4 + 3][n] = w.w;
    }
    __syncthreads();
#pragma unroll
    for (int k = 0; k < 32; k++) {
      float2 a = *(const float2*)&Ut[k0 + k][tt * 2];
      float4 w0 = *(const float4*)&Ws[k][tm * 4];
      float4 w1v = *(const float4*)&Ws[k][64 + tm * 4];
      acc[0][0] = fmaf(a.x, w0.x, acc[0][0]);
      acc[0][1] = fmaf(a.x, w0.y, acc[0][1]);
      acc[0][2] = fmaf(a.x, w0.z, acc[0][2]);
      acc[0][3] = fmaf(a.x, w0.w, acc[0][3]);
      acc[0][4] = fmaf(a.x, w1v.x, acc[0][4]);
      acc[0][5] = fmaf(a.x, w1v.y, acc[0][5]);
      acc[0][6] = fmaf(a.x, w1v.z, acc[0][6]);
      acc[0][7] = fmaf(a.x, w1v.w, acc[0][7]);
      acc[1][0] = fmaf(a.y, w0.x, acc[1][0]);
      acc[1][1] = fmaf(a.y, w0.y, acc[1][1]);
      acc[1][2] = fmaf(a.y, w0.z, acc[1][2]);
      acc[1][3] = fmaf(a.y, w0.w, acc[1][3]);
      acc[1][4] = fmaf(a.y, w1v.x, acc[1][4]);
      acc[1][5] = fmaf(a.y, w1v.y, acc[1][5]);
      acc[1][6] = fmaf(a.y, w1v.z, acc[1][6]);
      acc[1][7] = fmaf(a.y, w1v.w, acc[1][7]);
    }
    __syncthreads();
  }
  const float* nw = n2w + l * 128;
  const float* nb = n2b + l * 128;
#pragma unroll
  for (int r = 0; r < 2; r++) {
    int t = t0 + tt * 2 + r;
    float4 h0 = make_float4(0.f, 0.f, 0.f, 0.f);
    float4 h1 = make_float4(0.f, 0.f, 0.f, 0.f);
    if (t < L_SEQ) {
      const float* hp = &H1[((size_t)b * L_SEQ + t) * 128];
      h0 = *(const float4*)&hp[tm * 4];
      h1 = *(const float4*)&hp[64 + tm * 4];
    }
    float v[8];
    v[0] = acc[r][0] + b2[l * 128 + tm * 4 + 0] + h0.x;
    v[1] = acc[r][1] + b2[l * 128 + tm * 4 + 1] + h0.y;
    v[2] = acc[r][2] + b2[l * 128 + tm * 4 + 2] + h0.z;
    v[3] = acc[r][3] + b2[l * 128 + tm * 4 + 3] + h0.w;
    v[4] = acc[r][4] + b2[l * 128 + 64 + tm * 4 + 0] + h1.x;
    v[5] = acc[r][5] + b2[l * 128 + 64 + tm * 4 + 1] + h1.y;
    v[6] = acc[r][6] + b2[l * 128 + 64 + tm * 4 + 2] + h1.z;
    v[7] = acc[r][7] + b2[l * 128 + 64 + tm * 4 + 3] + h1.w;
    float s1 = 0.f, s2 = 0.f;
#pragma unroll
    for (int jq = 0; jq < 8; jq++) { s1 += v[jq]; s2 += v[jq] * v[jq]; }
#pragma unroll
    for (int msk = 1; msk < 16; msk <<= 1) {
      s1 += __shfl_xor(s1, msk);
      s2 += __shfl_xor(s2, msk);
    }
    float mean = s1 * (1.f / 128.f);
    float rstd = rsqrtf(s2 * (1.f / 128.f) - mean * mean + 1e-5f);
    if (t < L_SEQ) {
      float* dst = &Hout[((size_t)b * L_SEQ + t) * 128];
      float4 o0 = make_float4((v[0] - mean) * rstd * nw[tm * 4 + 0] + nb[tm * 4 + 0],
                              (v[1] - mean) * rstd * nw[tm * 4 + 1] + nb[tm * 4 + 1],
                              (v[2] - mean) * rstd * nw[tm * 4 + 2] + nb[tm * 4 + 2],
                              (v[3] - mean) * rstd * nw[tm * 4 + 3] + nb[tm * 4 + 3]);
      float4 o1 = make_float4((v[4] - mean) * rstd * nw[64 + tm * 4 + 0] + nb[64 + tm * 4 + 0],
                              (v[5] - mean) * rstd * nw[64 + tm * 4 + 1] + nb[64 + tm * 4 + 1],
                              (v[6] - mean) * rstd * nw[64 + tm * 4 + 2] + nb[64 + tm * 4 + 2],
                              (v[7] - mean) * rstd * nw[64 + tm * 4 + 3] + nb[64 + tm * 4 + 3]);
      *(float4*)&dst[tm * 4] = o0;
      *(float4*)&dst[64 + tm * 4] = o1;
    }
  }
}

// ---------------------------------------------------------------------------
// k_final  (round-3, proven)
// ---------------------------------------------------------------------------
__global__ __launch_bounds__(256) void k_final(
    const float* __restrict__ Hsrc, const float* __restrict__ fw,
    const float* __restrict__ fb, const float* __restrict__ pw,
    const float* __restrict__ pb, float* __restrict__ out) {
  int b = blockIdx.y;
  int v0 = blockIdx.x * 16;
  int tid = threadIdx.x;
  __shared__ float At[128][17];
  __shared__ float Ws[32][97];
  __shared__ float Os[96][17];
  for (int i = 0; i < 8; i++) {
    int e = tid + i * 256;
    int k = e & 127, tl = e >> 7;
    At[k][tl] = Hsrc[((size_t)b * L_SEQ + v0 + tl) * 128 + k];
  }
  __syncthreads();
  {
    int g = tid & 15, tl = tid >> 4;
    float s1 = 0.f, s2 = 0.f;
#pragma unroll
    for (int kk = 0; kk < 8; kk++) {
      float v = At[g * 8 + kk][tl];
      s1 += v;
      s2 += v * v;
    }
#pragma unroll
    for (int msk = 1; msk < 16; msk <<= 1) {
      s1 += __shfl_xor(s1, msk);
      s2 += __shfl_xor(s2, msk);
    }
    float mean = s1 * (1.f / 128.f);
    float rstd = rsqrtf(s2 * (1.f / 128.f) - mean * mean + 1e-5f);
#pragma unroll
    for (int kk = 0; kk < 8; kk++) {
      int k = g * 8 + kk;
      At[k][tl] = (At[k][tl] - mean) * rstd * fw[k] + fb[k];
    }
  }
  __syncthreads();
  int tm = tid & 15, tt = tid >> 4;
  float acc[6] = {0.f};
  for (int k0 = 0; k0 < 128; k0 += 32) {
    for (int i = 0; i < 12; i++) {
      int e = tid + i * 256;
      int ki = e & 31, p = e >> 5;
      Ws[ki][p] = pw[(size_t)p * 128 + k0 + ki];
    }
    __syncthreads();
    for (int ki = 0; ki < 32; ki++) {
      float a = At[k0 + ki][tt];
#pragma unroll
      for (int jq = 0; jq < 6; jq++)
        acc[jq] = fmaf(a, Ws[ki][tm + jq * 16], acc[jq]);
    }
    __syncthreads();
  }
#pragma unroll
  for (int jq = 0; jq < 6; jq++) {
    int p = tm + jq * 16;
    Os[p][tt] = acc[jq] + pb[p];
  }
  __syncthreads();
  for (int i = 0; i < 6; i++) {
    int e = tid + i * 256;
    int vi = e & 15, p = e >> 4;
    out[((size_t)b * 96 + p) * 1024 + v0 + vi] = Os[p][vi];
  }
}

// ---------------------------------------------------------------------------
extern "C" void kernel_launch(void* const* d_in, const int* in_sizes, int n_in,
                              void* d_out, int out_size, void* d_ws, size_t ws_size,
                              hipStream_t stream) {
  (void)in_sizes; (void)n_in; (void)out_size; (void)ws_size;
  const float* x_enc  = (const float*)d_in[0];
  const float* x_mark = (const float*)d_in[1];
  const float* emb_w  = (const float*)d_in[4];
  const float* emb_b  = (const float*)d_in[5];
  const float* ipw    = (const float*)d_in[6];
  const float* cw     = (const float*)d_in[7];
  const float* cb     = (const float*)d_in[8];
  const float* xpw    = (const float*)d_in[9];
  const float* dpw    = (const float*)d_in[10];
  const float* dpb    = (const float*)d_in[11];
  const float* A_log  = (const float*)d_in[12];
  const float* Dpar   = (const float*)d_in[13];
  const float* opw    = (const float*)d_in[14];
  const float* n1w    = (const float*)d_in[15];
  const float* n1b    = (const float*)d_in[16];
  const float* n2w    = (const float*)d_in[17];
  const float* n2b    = (const float*)d_in[18];
  const float* fw1    = (const float*)d_in[19];
  const float* fb1    = (const float*)d_in[20];
  const float* fw2    = (const float*)d_in[21];
  const float* fb2    = (const float*)d_in[22];
  const float* fnw    = (const float*)d_in[23];
  const float* fnb    = (const float*)d_in[24];
  const float* pw     = (const float*)d_in[25];
  const float* pb     = (const float*)d_in[26];

  float* ws   = (float*)d_ws;
  float* H    = ws + OFF_H;
  float* H1   = ws + OFF_H1;
  float* XZ   = ws + OFF_XZ;
  float* XCT  = ws + OFF_XCT;
  float* DLT  = ws + OFF_DLT;
  float* BmT  = ws + OFF_BMT;
  float* CmT  = ws + OFF_CMT;
  float* YT   = ws + OFF_YT;
  float* sumH = ws + OFF_H1;             // overlay: H1 unused during scan
  float* sumP = ws + OFF_H1 + SZ_SUM;

  k_embed<<<dim3(33, 8), 256, 0, stream>>>(x_enc, x_mark, emb_w, emb_b, H);
  for (int l = 0; l < 2; l++) {
    k_xz<<<dim3(33, 8, 4), 256, 0, stream>>>(H, ipw, XZ, l);
    k_mid<<<dim3(33, 8, 2), 256, 0, stream>>>(XZ, cw, cb, xpw, dpw, dpb,
                                              XCT, DLT, BmT, CmT, l);
    k_scan1<<<dim3(16, 8, 16), 64, 0, stream>>>(DLT, XCT, BmT, A_log,
                                                sumH, sumP, l);
    k_scan2<<<dim3(16, 8, 16), 64, 0, stream>>>(DLT, XCT, BmT, CmT, XZ,
                                                A_log, Dpar, sumH, sumP, YT, l);
    k_out<<<dim3(33, 8), 256, 0, stream>>>(YT, H, opw, n1w, n1b, H1, l);
    k_ffn<<<dim3(33, 8), 256, 0, stream>>>(H1, fw1, fb1, fw2, fb2, n2w, n2b, H, l);
  }
  k_final<<<dim3(64, 8), 256, 0, stream>>>(H, fnw, fnb, pw, pb, (float*)d_out);
}